// Round 2
// baseline (8386.536 us; speedup 1.0000x reference)
//
#include <hip/hip_runtime.h>

// ---------- bf16 helpers (manual, RNE) ----------
__device__ __forceinline__ float bf2f(unsigned short u) {
  union { unsigned int i; float f; } c; c.i = ((unsigned int)u) << 16; return c.f;
}
__device__ __forceinline__ unsigned short f2bf(float f) {
  union { float f; unsigned int i; } c; c.f = f;
  unsigned int i = c.i;
  i += 0x7fffu + ((i >> 16) & 1u);
  return (unsigned short)(i >> 16);
}

// Geometry: x is (bt=8, C=128, 64, 64); bt = b*4 + t (b=2, t=4).
// Head group g (0..3): patch p = 1<<(g+1), dk = 32 channels.
// Packed token layout per group: (b, l, d), l over (t, oh, ow), d over (dk, ph, pw).
// L*D = 524288 (=1<<19) for every group; group base offset = g<<20 elements.

// ---------- QKV projection GEMM with pack epilogue ----------
__global__ __launch_bounds__(256) void qkv_gemm(
    const float* __restrict__ X, const float* __restrict__ W,
    const float* __restrict__ Bi, unsigned short* __restrict__ outp, int is_q) {
  __shared__ __align__(16) float As[16][36];
  __shared__ __align__(16) float Bs[16][36];
  int tid = threadIdx.x;
  int tx = tid & 15, ty = tid >> 4;
  int n0 = blockIdx.x * 16, m0 = blockIdx.y * 16, bt = blockIdx.z;
  const float* Xb = X + ((size_t)bt << 19);
  float acc = 0.f;
  for (int k0 = 0; k0 < 128; k0 += 32) {
    __syncthreads();
    {
      int lin = tid, r = lin >> 5, kk = lin & 31;
      As[r][kk] = W[(m0 + r) * 128 + k0 + kk];
      lin += 256; r = lin >> 5; kk = lin & 31;
      As[r][kk] = W[(m0 + r) * 128 + k0 + kk];
    }
    {
      int lin = tid, kk = lin >> 4, n = lin & 15;
      Bs[n][kk] = Xb[(k0 + kk) * 4096 + n0 + n];
      lin += 256; kk = lin >> 4; n = lin & 15;
      Bs[n][kk] = Xb[(k0 + kk) * 4096 + n0 + n];
    }
    __syncthreads();
#pragma unroll
    for (int kq = 0; kq < 8; kq++) {
      float4 a = *(const float4*)&As[ty][kq * 4];
      float4 b = *(const float4*)&Bs[tx][kq * 4];
      acc += a.x * b.x + a.y * b.y + a.z * b.z + a.w * b.w;
    }
  }
  int c = m0 + ty, pix = n0 + tx;
  float val = acc + Bi[c];
  int g = c >> 5, dk = c & 31;
  int sh = g + 1, msk = (1 << sh) - 1;
  int h = pix >> 6, w = pix & 63;
  int ohn = 64 >> sh;
  int b = bt >> 2, t_i = bt & 3;
  int l = (t_i * ohn + (h >> sh)) * ohn + (w >> sh);
  int Dg = 32 << (2 * sh);
  int d = (dk << (2 * sh)) + ((h & msk) << sh) + (w & msk);
  if (is_q) val *= rsqrtf((float)Dg);
  outp[((size_t)g << 20) + ((size_t)b << 19) + (size_t)l * Dg + d] = f2bf(val);
}

// ---------- S = Q K^T for groups 1..3 (bf16 in, f32 out) ----------
__global__ __launch_bounds__(256) void s_gemm(
    const unsigned short* __restrict__ Q, const unsigned short* __restrict__ K,
    float* __restrict__ S, int L, int D) {
  __shared__ __align__(16) float As[16][36];
  __shared__ __align__(16) float Bs[16][36];
  int tid = threadIdx.x;
  int tx = tid & 15, ty = tid >> 4;
  int n0 = blockIdx.x * 16, m0 = blockIdx.y * 16, b = blockIdx.z;
  const unsigned short* Qb = Q + ((size_t)b << 19);
  const unsigned short* Kb = K + ((size_t)b << 19);
  float acc = 0.f;
  for (int k0 = 0; k0 < D; k0 += 32) {
    __syncthreads();
    {
      int lin = tid, r = lin >> 5, kk = lin & 31;
      As[r][kk] = bf2f(Qb[(size_t)(m0 + r) * D + k0 + kk]);
      Bs[r][kk] = bf2f(Kb[(size_t)(n0 + r) * D + k0 + kk]);
      lin += 256; r = lin >> 5; kk = lin & 31;
      As[r][kk] = bf2f(Qb[(size_t)(m0 + r) * D + k0 + kk]);
      Bs[r][kk] = bf2f(Kb[(size_t)(n0 + r) * D + k0 + kk]);
    }
    __syncthreads();
#pragma unroll
    for (int kq = 0; kq < 8; kq++) {
      float4 a = *(const float4*)&As[ty][kq * 4];
      float4 b4 = *(const float4*)&Bs[tx][kq * 4];
      acc += a.x * b4.x + a.y * b4.y + a.z * b4.z + a.w * b4.w;
    }
  }
  S[((size_t)b * L + m0 + ty) * L + n0 + tx] = acc;
}

// ---------- row softmax, in place ----------
__global__ __launch_bounds__(256) void softmax_rows(float* __restrict__ S, int L) {
  __shared__ float red[256];
  int tid = threadIdx.x;
  float* p = S + (size_t)blockIdx.x * L;
  float mx = -1e30f;
  for (int e = tid; e < L; e += 256) mx = fmaxf(mx, p[e]);
  red[tid] = mx; __syncthreads();
  for (int s = 128; s > 0; s >>= 1) {
    if (tid < s) red[tid] = fmaxf(red[tid], red[tid + s]);
    __syncthreads();
  }
  mx = red[0]; __syncthreads();
  float sm = 0.f;
  for (int e = tid; e < L; e += 256) {
    float v = __expf(p[e] - mx);
    p[e] = v; sm += v;
  }
  red[tid] = sm; __syncthreads();
  for (int s = 128; s > 0; s >>= 1) {
    if (tid < s) red[tid] += red[tid + s];
    __syncthreads();
  }
  float inv = 1.f / red[0];
  for (int e = tid; e < L; e += 256) p[e] *= inv;
}

// ---------- O = P V for groups 1..3 ----------
__global__ __launch_bounds__(256) void pv_gemm(
    const float* __restrict__ P, const unsigned short* __restrict__ V,
    float* __restrict__ O, int L, int D) {
  __shared__ __align__(16) float As[16][36];
  __shared__ __align__(16) float Bs[16][36];
  int tid = threadIdx.x;
  int tx = tid & 15, ty = tid >> 4;
  int n0 = blockIdx.x * 16, m0 = blockIdx.y * 16, b = blockIdx.z;
  const unsigned short* Vb = V + ((size_t)b << 19);
  const float* Pb = P + (size_t)b * L * L;
  float acc = 0.f;
  for (int k0 = 0; k0 < L; k0 += 32) {
    __syncthreads();
    {
      int lin = tid, r = lin >> 5, kk = lin & 31;
      As[r][kk] = Pb[(size_t)(m0 + r) * L + k0 + kk];
      lin += 256; r = lin >> 5; kk = lin & 31;
      As[r][kk] = Pb[(size_t)(m0 + r) * L + k0 + kk];
      lin = tid; int k2 = lin >> 4, n = lin & 15;
      Bs[n][k2] = bf2f(Vb[(size_t)(k0 + k2) * D + n0 + n]);
      lin += 256; k2 = lin >> 4; n = lin & 15;
      Bs[n][k2] = bf2f(Vb[(size_t)(k0 + k2) * D + n0 + n]);
    }
    __syncthreads();
#pragma unroll
    for (int kq = 0; kq < 8; kq++) {
      float4 a = *(const float4*)&As[ty][kq * 4];
      float4 b4 = *(const float4*)&Bs[tx][kq * 4];
      acc += a.x * b4.x + a.y * b4.y + a.z * b4.z + a.w * b4.w;
    }
  }
  O[((size_t)b << 19) + (size_t)(m0 + ty) * D + n0 + tx] = acc;
}

// ---------- flash attention for group 0 (L=4096, D=128) ----------
// Br=16 queries/WG, Kc=32 keys/chunk (LDS 44.5 KB < 64 KB static cap).
__global__ __launch_bounds__(256) void flash_g0(
    const unsigned short* __restrict__ Q, const unsigned short* __restrict__ K,
    const unsigned short* __restrict__ V, float* __restrict__ O) {
  constexpr int SD = 132;  // padded stride
  __shared__ __align__(16) float Qs[16][SD];
  __shared__ __align__(16) float Ks[32][SD];
  __shared__ __align__(16) float Vs[32][SD];
  __shared__ float Ps[16][36];
  int tid = threadIdx.x;
  int b = blockIdx.x >> 8;
  int q0 = (blockIdx.x & 255) << 4;
  int r = tid >> 4, hx = tid & 15;
  size_t bofs = (size_t)b << 19;
  for (int e = tid; e < 16 * 128; e += 256) {
    int rr = e >> 7, dd = e & 127;
    Qs[rr][dd] = bf2f(Q[bofs + (size_t)(q0 + rr) * 128 + dd]);
  }
  float m_i = -1e30f, l_i = 0.f;
  float Ov[8];
#pragma unroll
  for (int j = 0; j < 8; j++) Ov[j] = 0.f;
  for (int k0 = 0; k0 < 4096; k0 += 32) {
    __syncthreads();  // previous PV done before restaging
    for (int e = tid; e < 32 * 32; e += 256) {
      int rr = e >> 5, d4 = (e & 31) << 2;
      ushort4 kv = *(const ushort4*)(K + bofs + (size_t)(k0 + rr) * 128 + d4);
      Ks[rr][d4 + 0] = bf2f(kv.x); Ks[rr][d4 + 1] = bf2f(kv.y);
      Ks[rr][d4 + 2] = bf2f(kv.z); Ks[rr][d4 + 3] = bf2f(kv.w);
      ushort4 vv = *(const ushort4*)(V + bofs + (size_t)(k0 + rr) * 128 + d4);
      Vs[rr][d4 + 0] = bf2f(vv.x); Vs[rr][d4 + 1] = bf2f(vv.y);
      Vs[rr][d4 + 2] = bf2f(vv.z); Vs[rr][d4 + 3] = bf2f(vv.w);
    }
    __syncthreads();
    float sv[2];
    sv[0] = sv[1] = 0.f;
    for (int d4 = 0; d4 < 128; d4 += 4) {
      float4 q4 = *(const float4*)&Qs[r][d4];
#pragma unroll
      for (int mm = 0; mm < 2; mm++) {
        float4 k4 = *(const float4*)&Ks[hx + (mm << 4)][d4];
        sv[mm] += q4.x * k4.x + q4.y * k4.y + q4.z * k4.z + q4.w * k4.w;
      }
    }
    float cmax = fmaxf(sv[0], sv[1]);
#pragma unroll
    for (int sft = 1; sft < 16; sft <<= 1)
      cmax = fmaxf(cmax, __shfl_xor(cmax, sft));
    float mnew = fmaxf(m_i, cmax);
    float alpha = __expf(m_i - mnew);
    float psum = 0.f;
#pragma unroll
    for (int mm = 0; mm < 2; mm++) {
      float pv = __expf(sv[mm] - mnew);
      Ps[r][hx + (mm << 4)] = pv;
      psum += pv;
    }
#pragma unroll
    for (int sft = 1; sft < 16; sft <<= 1)
      psum += __shfl_xor(psum, sft);
    l_i = l_i * alpha + psum;
    m_i = mnew;
#pragma unroll
    for (int j = 0; j < 8; j++) Ov[j] *= alpha;
    __syncthreads();  // Ps visible to whole row group
    for (int kc = 0; kc < 32; kc++) {
      float pv = Ps[r][kc];
      float4 v0 = *(const float4*)&Vs[kc][hx << 2];
      float4 v1 = *(const float4*)&Vs[kc][64 + (hx << 2)];
      Ov[0] += pv * v0.x; Ov[1] += pv * v0.y; Ov[2] += pv * v0.z; Ov[3] += pv * v0.w;
      Ov[4] += pv * v1.x; Ov[5] += pv * v1.y; Ov[6] += pv * v1.z; Ov[7] += pv * v1.w;
    }
  }
  float inv = 1.f / l_i;
  float* Ob = O + bofs + (size_t)(q0 + r) * 128;
  float4 o0 = make_float4(Ov[0] * inv, Ov[1] * inv, Ov[2] * inv, Ov[3] * inv);
  float4 o1 = make_float4(Ov[4] * inv, Ov[5] * inv, Ov[6] * inv, Ov[7] * inv);
  *(float4*)&Ob[hx << 2] = o0;
  *(float4*)&Ob[64 + (hx << 2)] = o1;
}

// ---------- unpack packed attention output back to (bt, c, h, w) ----------
__global__ __launch_bounds__(256) void unpack_att(
    const float* __restrict__ opk, float* __restrict__ att) {
  int idx = blockIdx.x * 256 + threadIdx.x;
  int w = idx & 63, h = (idx >> 6) & 63, c = (idx >> 12) & 127, bt = idx >> 19;
  int g = c >> 5, dk = c & 31;
  int sh = g + 1, msk = (1 << sh) - 1;
  int ohn = 64 >> sh;
  int b = bt >> 2, t_i = bt & 3;
  int l = (t_i * ohn + (h >> sh)) * ohn + (w >> sh);
  int Dg = 32 << (2 * sh);
  int d = (dk << (2 * sh)) + ((h & msk) << sh) + (w & msk);
  att[idx] = opk[((size_t)g << 20) + ((size_t)b << 19) + (size_t)l * Dg + d];
}

// ---------- 3x3 conv (dilated), bias + leaky(0.2) + optional residual ----------
template <int DIL, bool RES>
__global__ __launch_bounds__(256) void conv3(
    const float* __restrict__ X, const float* __restrict__ Wt,
    const float* __restrict__ Bi, const float* __restrict__ Rs,
    float* __restrict__ Y) {
  int w = threadIdx.x & 63;
  int wave = threadIdx.x >> 6;
  int o = blockIdx.x * 8 + wave * 2;
  int h = blockIdx.y;
  int bt = blockIdx.z;
  float a0 = Bi[o], a1 = Bi[o + 1];
  const float* xb = X + ((size_t)bt << 19);
  const float* w0 = Wt + (size_t)o * 1152;
  const float* w1 = w0 + 1152;
  for (int i = 0; i < 128; i++) {
    const float* xr = xb + i * 4096;
    const float* wi0 = w0 + i * 9;
    const float* wi1 = w1 + i * 9;
#pragma unroll
    for (int kh = 0; kh < 3; kh++) {
      int hh = h + DIL * (kh - 1);
      if ((unsigned)hh < 64u) {
        const float* row = xr + hh * 64;
#pragma unroll
        for (int kw = 0; kw < 3; kw++) {
          int ww = w + DIL * (kw - 1);
          if ((unsigned)ww < 64u) {
            float xv = row[ww];
            a0 += wi0[kh * 3 + kw] * xv;
            a1 += wi1[kh * 3 + kw] * xv;
          }
        }
      }
    }
  }
  size_t idx = (((size_t)bt * 128 + o) * 64 + h) * 64 + w;
  float z0 = a0 > 0.f ? a0 : 0.2f * a0;
  float z1 = a1 > 0.f ? a1 : 0.2f * a1;
  if (RES) { z0 += Rs[idx]; z1 += Rs[idx + 4096]; }
  Y[idx] = z0;
  Y[idx + 4096] = z1;
}

extern "C" void kernel_launch(void* const* d_in, const int* in_sizes, int n_in,
                              void* d_out, int out_size, void* d_ws, size_t ws_size,
                              hipStream_t stream) {
  (void)in_sizes; (void)n_in; (void)out_size; (void)ws_size;
  const float* x   = (const float*)d_in[0];
  const float* Wq  = (const float*)d_in[1];
  const float* bq  = (const float*)d_in[2];
  const float* Wk  = (const float*)d_in[3];
  const float* bk  = (const float*)d_in[4];
  const float* Wv  = (const float*)d_in[5];
  const float* bv  = (const float*)d_in[6];
  const float* Wo  = (const float*)d_in[7];
  const float* bo  = (const float*)d_in[8];
  const float* Wf1 = (const float*)d_in[9];
  const float* bf1 = (const float*)d_in[10];
  const float* Wf2 = (const float*)d_in[11];
  const float* bf2 = (const float*)d_in[12];
  float* out = (float*)d_out;

  // workspace layout (total 101,220,352 B)
  char* wsb = (char*)d_ws;
  float* xcur = (float*)(wsb);                               // 16,777,216
  float* S1   = (float*)(wsb + 16777216);                    //  8,388,608
  float* S2   = (float*)(wsb + 25165824);                    //    524,288
  float* S3   = (float*)(wsb + 25690112);                    //     32,768
  float* opk  = (float*)(wsb + 25722880);                    // 16,777,216
  float* att  = (float*)(wsb + 42500096);                    // 16,777,216
  unsigned short* Qp = (unsigned short*)(wsb + 59277312);    //  8,388,608
  unsigned short* Kp = (unsigned short*)(wsb + 67665920);    //  8,388,608
  unsigned short* Vp = (unsigned short*)(wsb + 76054528);    //  8,388,608
  float* f1   = (float*)(wsb + 84443136);                    // 16,777,216

  hipMemcpyAsync(xcur, x, 16777216, hipMemcpyDeviceToDevice, stream);

  const int Ls[3] = {1024, 256, 64};
  const int Ds[3] = {512, 2048, 8192};
  float* Sb[3] = {S1, S2, S3};
  dim3 blk(256);

  for (int layer = 0; layer < 2; layer++) {
    const float* wq  = Wq  + layer * 16384;
    const float* wk  = Wk  + layer * 16384;
    const float* wv  = Wv  + layer * 16384;
    const float* bq_ = bq  + layer * 128;
    const float* bk_ = bk  + layer * 128;
    const float* bv_ = bv  + layer * 128;
    const float* wo  = Wo  + layer * 147456;
    const float* bo_ = bo  + layer * 128;
    const float* wf1 = Wf1 + layer * 147456;
    const float* bf1_ = bf1 + layer * 128;
    const float* wf2 = Wf2 + layer * 147456;
    const float* bf2_ = bf2 + layer * 128;

    qkv_gemm<<<dim3(256, 8, 8), blk, 0, stream>>>(xcur, wq, bq_, Qp, 1);
    qkv_gemm<<<dim3(256, 8, 8), blk, 0, stream>>>(xcur, wk, bk_, Kp, 0);
    qkv_gemm<<<dim3(256, 8, 8), blk, 0, stream>>>(xcur, wv, bv_, Vp, 0);

    flash_g0<<<dim3(512), blk, 0, stream>>>(Qp, Kp, Vp, opk);

    for (int gg = 0; gg < 3; gg++) {
      int g = gg + 1;
      size_t go = (size_t)g << 20;
      int L = Ls[gg], D = Ds[gg];
      s_gemm<<<dim3(L / 16, L / 16, 2), blk, 0, stream>>>(Qp + go, Kp + go, Sb[gg], L, D);
      softmax_rows<<<dim3(2 * L), blk, 0, stream>>>(Sb[gg], L);
      pv_gemm<<<dim3(D / 16, L / 16, 2), blk, 0, stream>>>(Sb[gg], Vp + go, opk + go, L, D);
    }

    unpack_att<<<dim3(16384), blk, 0, stream>>>(opk, att);

    conv3<1, true><<<dim3(16, 64, 8), blk, 0, stream>>>(att, wo, bo_, xcur, xcur);
    conv3<2, false><<<dim3(16, 64, 8), blk, 0, stream>>>(xcur, wf1, bf1_, nullptr, f1);
    float* dst = (layer == 1) ? out : xcur;
    conv3<1, true><<<dim3(16, 64, 8), blk, 0, stream>>>(f1, wf2, bf2_, xcur, dst);
  }
}

// Round 3
// 2571.088 us; speedup vs baseline: 3.2619x; 3.2619x over previous
//
#include <hip/hip_runtime.h>

// ---------- bf16 helpers (manual, RNE) ----------
__device__ __forceinline__ float bf2f(unsigned short u) {
  union { unsigned int i; float f; } c; c.i = ((unsigned int)u) << 16; return c.f;
}
__device__ __forceinline__ unsigned short f2bf(float f) {
  union { float f; unsigned int i; } c; c.f = f;
  unsigned int i = c.i;
  i += 0x7fffu + ((i >> 16) & 1u);
  return (unsigned short)(i >> 16);
}

typedef __attribute__((ext_vector_type(8))) short bf16x8;
typedef __attribute__((ext_vector_type(4))) float f32x4;

// Geometry: x is (bt=8, C=128, 64, 64); bt = b*4 + t (b=2, t=4).
// Head group g (0..3): patch p = 1<<(g+1), dk = 32 channels.
// Packed token layout per group: (b, l, d); L*D = 1<<19; group base = g<<20.

// ---------- QKV projection GEMM with pack epilogue ----------
__global__ __launch_bounds__(256) void qkv_gemm(
    const float* __restrict__ X, const float* __restrict__ W,
    const float* __restrict__ Bi, unsigned short* __restrict__ outp, int is_q) {
  __shared__ __align__(16) float As[16][36];
  __shared__ __align__(16) float Bs[16][36];
  int tid = threadIdx.x;
  int tx = tid & 15, ty = tid >> 4;
  int n0 = blockIdx.x * 16, m0 = blockIdx.y * 16, bt = blockIdx.z;
  const float* Xb = X + ((size_t)bt << 19);
  float acc = 0.f;
  for (int k0 = 0; k0 < 128; k0 += 32) {
    __syncthreads();
    {
      int lin = tid, r = lin >> 5, kk = lin & 31;
      As[r][kk] = W[(m0 + r) * 128 + k0 + kk];
      lin += 256; r = lin >> 5; kk = lin & 31;
      As[r][kk] = W[(m0 + r) * 128 + k0 + kk];
    }
    {
      int lin = tid, kk = lin >> 4, n = lin & 15;
      Bs[n][kk] = Xb[(k0 + kk) * 4096 + n0 + n];
      lin += 256; kk = lin >> 4; n = lin & 15;
      Bs[n][kk] = Xb[(k0 + kk) * 4096 + n0 + n];
    }
    __syncthreads();
#pragma unroll
    for (int kq = 0; kq < 8; kq++) {
      float4 a = *(const float4*)&As[ty][kq * 4];
      float4 b = *(const float4*)&Bs[tx][kq * 4];
      acc += a.x * b.x + a.y * b.y + a.z * b.z + a.w * b.w;
    }
  }
  int c = m0 + ty, pix = n0 + tx;
  float val = acc + Bi[c];
  int g = c >> 5, dk = c & 31;
  int sh = g + 1, msk = (1 << sh) - 1;
  int h = pix >> 6, w = pix & 63;
  int ohn = 64 >> sh;
  int b = bt >> 2, t_i = bt & 3;
  int l = (t_i * ohn + (h >> sh)) * ohn + (w >> sh);
  int Dg = 32 << (2 * sh);
  int d = (dk << (2 * sh)) + ((h & msk) << sh) + (w & msk);
  if (is_q) val *= rsqrtf((float)Dg);
  outp[((size_t)g << 20) + ((size_t)b << 19) + (size_t)l * Dg + d] = f2bf(val);
}

// ---------- S = Q K^T for groups 1..3 (bf16 in, f32 out) ----------
__global__ __launch_bounds__(256) void s_gemm(
    const unsigned short* __restrict__ Q, const unsigned short* __restrict__ K,
    float* __restrict__ S, int L, int D) {
  __shared__ __align__(16) float As[16][36];
  __shared__ __align__(16) float Bs[16][36];
  int tid = threadIdx.x;
  int tx = tid & 15, ty = tid >> 4;
  int n0 = blockIdx.x * 16, m0 = blockIdx.y * 16, b = blockIdx.z;
  const unsigned short* Qb = Q + ((size_t)b << 19);
  const unsigned short* Kb = K + ((size_t)b << 19);
  float acc = 0.f;
  for (int k0 = 0; k0 < D; k0 += 32) {
    __syncthreads();
    {
      int lin = tid, r = lin >> 5, kk = lin & 31;
      As[r][kk] = bf2f(Qb[(size_t)(m0 + r) * D + k0 + kk]);
      Bs[r][kk] = bf2f(Kb[(size_t)(n0 + r) * D + k0 + kk]);
      lin += 256; r = lin >> 5; kk = lin & 31;
      As[r][kk] = bf2f(Qb[(size_t)(m0 + r) * D + k0 + kk]);
      Bs[r][kk] = bf2f(Kb[(size_t)(n0 + r) * D + k0 + kk]);
    }
    __syncthreads();
#pragma unroll
    for (int kq = 0; kq < 8; kq++) {
      float4 a = *(const float4*)&As[ty][kq * 4];
      float4 b4 = *(const float4*)&Bs[tx][kq * 4];
      acc += a.x * b4.x + a.y * b4.y + a.z * b4.z + a.w * b4.w;
    }
  }
  S[((size_t)b * L + m0 + ty) * L + n0 + tx] = acc;
}

// ---------- row softmax, in place ----------
__global__ __launch_bounds__(256) void softmax_rows(float* __restrict__ S, int L) {
  __shared__ float red[256];
  int tid = threadIdx.x;
  float* p = S + (size_t)blockIdx.x * L;
  float mx = -1e30f;
  for (int e = tid; e < L; e += 256) mx = fmaxf(mx, p[e]);
  red[tid] = mx; __syncthreads();
  for (int s = 128; s > 0; s >>= 1) {
    if (tid < s) red[tid] = fmaxf(red[tid], red[tid + s]);
    __syncthreads();
  }
  mx = red[0]; __syncthreads();
  float sm = 0.f;
  for (int e = tid; e < L; e += 256) {
    float v = __expf(p[e] - mx);
    p[e] = v; sm += v;
  }
  red[tid] = sm; __syncthreads();
  for (int s = 128; s > 0; s >>= 1) {
    if (tid < s) red[tid] += red[tid + s];
    __syncthreads();
  }
  float inv = 1.f / red[0];
  for (int e = tid; e < L; e += 256) p[e] *= inv;
}

// ---------- O = P V for groups 1..3 ----------
__global__ __launch_bounds__(256) void pv_gemm(
    const float* __restrict__ P, const unsigned short* __restrict__ V,
    float* __restrict__ O, int L, int D) {
  __shared__ __align__(16) float As[16][36];
  __shared__ __align__(16) float Bs[16][36];
  int tid = threadIdx.x;
  int tx = tid & 15, ty = tid >> 4;
  int n0 = blockIdx.x * 16, m0 = blockIdx.y * 16, b = blockIdx.z;
  const unsigned short* Vb = V + ((size_t)b << 19);
  const float* Pb = P + (size_t)b * L * L;
  float acc = 0.f;
  for (int k0 = 0; k0 < L; k0 += 32) {
    __syncthreads();
    {
      int lin = tid, r = lin >> 5, kk = lin & 31;
      As[r][kk] = Pb[(size_t)(m0 + r) * L + k0 + kk];
      lin += 256; r = lin >> 5; kk = lin & 31;
      As[r][kk] = Pb[(size_t)(m0 + r) * L + k0 + kk];
      lin = tid; int k2 = lin >> 4, n = lin & 15;
      Bs[n][k2] = bf2f(Vb[(size_t)(k0 + k2) * D + n0 + n]);
      lin += 256; k2 = lin >> 4; n = lin & 15;
      Bs[n][k2] = bf2f(Vb[(size_t)(k0 + k2) * D + n0 + n]);
    }
    __syncthreads();
#pragma unroll
    for (int kq = 0; kq < 8; kq++) {
      float4 a = *(const float4*)&As[ty][kq * 4];
      float4 b4 = *(const float4*)&Bs[tx][kq * 4];
      acc += a.x * b4.x + a.y * b4.y + a.z * b4.z + a.w * b4.w;
    }
  }
  O[((size_t)b << 19) + (size_t)(m0 + ty) * D + n0 + tx] = acc;
}

// ---------- flash attention for group 0 (L=4096, D=128) ----------
__global__ __launch_bounds__(256) void flash_g0(
    const unsigned short* __restrict__ Q, const unsigned short* __restrict__ K,
    const unsigned short* __restrict__ V, float* __restrict__ O) {
  constexpr int SD = 132;
  __shared__ __align__(16) float Qs[16][SD];
  __shared__ __align__(16) float Ks[32][SD];
  __shared__ __align__(16) float Vs[32][SD];
  __shared__ float Ps[16][36];
  int tid = threadIdx.x;
  int b = blockIdx.x >> 8;
  int q0 = (blockIdx.x & 255) << 4;
  int r = tid >> 4, hx = tid & 15;
  size_t bofs = (size_t)b << 19;
  for (int e = tid; e < 16 * 128; e += 256) {
    int rr = e >> 7, dd = e & 127;
    Qs[rr][dd] = bf2f(Q[bofs + (size_t)(q0 + rr) * 128 + dd]);
  }
  float m_i = -1e30f, l_i = 0.f;
  float Ov[8];
#pragma unroll
  for (int j = 0; j < 8; j++) Ov[j] = 0.f;
  for (int k0 = 0; k0 < 4096; k0 += 32) {
    __syncthreads();
    for (int e = tid; e < 32 * 32; e += 256) {
      int rr = e >> 5, d4 = (e & 31) << 2;
      ushort4 kv = *(const ushort4*)(K + bofs + (size_t)(k0 + rr) * 128 + d4);
      Ks[rr][d4 + 0] = bf2f(kv.x); Ks[rr][d4 + 1] = bf2f(kv.y);
      Ks[rr][d4 + 2] = bf2f(kv.z); Ks[rr][d4 + 3] = bf2f(kv.w);
      ushort4 vv = *(const ushort4*)(V + bofs + (size_t)(k0 + rr) * 128 + d4);
      Vs[rr][d4 + 0] = bf2f(vv.x); Vs[rr][d4 + 1] = bf2f(vv.y);
      Vs[rr][d4 + 2] = bf2f(vv.z); Vs[rr][d4 + 3] = bf2f(vv.w);
    }
    __syncthreads();
    float sv[2];
    sv[0] = sv[1] = 0.f;
    for (int d4 = 0; d4 < 128; d4 += 4) {
      float4 q4 = *(const float4*)&Qs[r][d4];
#pragma unroll
      for (int mm = 0; mm < 2; mm++) {
        float4 k4 = *(const float4*)&Ks[hx + (mm << 4)][d4];
        sv[mm] += q4.x * k4.x + q4.y * k4.y + q4.z * k4.z + q4.w * k4.w;
      }
    }
    float cmax = fmaxf(sv[0], sv[1]);
#pragma unroll
    for (int sft = 1; sft < 16; sft <<= 1)
      cmax = fmaxf(cmax, __shfl_xor(cmax, sft));
    float mnew = fmaxf(m_i, cmax);
    float alpha = __expf(m_i - mnew);
    float psum = 0.f;
#pragma unroll
    for (int mm = 0; mm < 2; mm++) {
      float pv = __expf(sv[mm] - mnew);
      Ps[r][hx + (mm << 4)] = pv;
      psum += pv;
    }
#pragma unroll
    for (int sft = 1; sft < 16; sft <<= 1)
      psum += __shfl_xor(psum, sft);
    l_i = l_i * alpha + psum;
    m_i = mnew;
#pragma unroll
    for (int j = 0; j < 8; j++) Ov[j] *= alpha;
    __syncthreads();
    for (int kc = 0; kc < 32; kc++) {
      float pv = Ps[r][kc];
      float4 v0 = *(const float4*)&Vs[kc][hx << 2];
      float4 v1 = *(const float4*)&Vs[kc][64 + (hx << 2)];
      Ov[0] += pv * v0.x; Ov[1] += pv * v0.y; Ov[2] += pv * v0.z; Ov[3] += pv * v0.w;
      Ov[4] += pv * v1.x; Ov[5] += pv * v1.y; Ov[6] += pv * v1.z; Ov[7] += pv * v1.w;
    }
  }
  float inv = 1.f / l_i;
  float* Ob = O + bofs + (size_t)(q0 + r) * 128;
  float4 o0 = make_float4(Ov[0] * inv, Ov[1] * inv, Ov[2] * inv, Ov[3] * inv);
  float4 o1 = make_float4(Ov[4] * inv, Ov[5] * inv, Ov[6] * inv, Ov[7] * inv);
  *(float4*)&Ob[hx << 2] = o0;
  *(float4*)&Ob[64 + (hx << 2)] = o1;
}

// ---------- unpack packed attention output to bf16 (bt,h,w,C) ----------
__global__ __launch_bounds__(256) void unpack_att_bf16(
    const float* __restrict__ opk, unsigned short* __restrict__ att) {
  int idx = blockIdx.x * 256 + threadIdx.x;  // (pix, oct)
  int oct = idx & 15, pix = idx >> 4;
  int w = pix & 63, h = (pix >> 6) & 63, bt = pix >> 12;
  int c0 = oct * 8;
  int g = c0 >> 5;
  int sh = g + 1, msk = (1 << sh) - 1;
  int ohn = 64 >> sh;
  int b = bt >> 2, t_i = bt & 3;
  int l = (t_i * ohn + (h >> sh)) * ohn + (w >> sh);
  int Dg = 32 << (2 * sh);
  int dbase = ((c0 & 31) << (2 * sh)) + ((h & msk) << sh) + (w & msk);
  const float* src = opk + ((size_t)g << 20) + ((size_t)b << 19) + (size_t)l * Dg;
  int dstep = 1 << (2 * sh);
  unsigned int pk[4];
#pragma unroll
  for (int j = 0; j < 4; j++) {
    unsigned short u0 = f2bf(src[dbase + (2 * j) * dstep]);
    unsigned short u1 = f2bf(src[dbase + (2 * j + 1) * dstep]);
    pk[j] = (unsigned int)u0 | ((unsigned int)u1 << 16);
  }
  *(uint4*)(att + ((size_t)pix * 128 + c0)) = make_uint4(pk[0], pk[1], pk[2], pk[3]);
}

// ---------- weight prep: (o,i,3,3) f32 -> (tap,o,i) bf16 ----------
__global__ __launch_bounds__(256) void wprep(const float* __restrict__ W,
                                             unsigned short* __restrict__ Wt) {
  int idx = blockIdx.x * 256 + threadIdx.x;  // 147456 total
  int tap = idx >> 14, rem = idx & 16383;
  int o = rem >> 7, i = rem & 127;
  Wt[idx] = f2bf(W[(size_t)(o * 128 + i) * 9 + tap]);
}

// ---------- MFMA implicit-GEMM 3x3 conv (LDS-free, direct global frags) ----------
// Input Xb: bf16 (bt,h,w,128). Weights Wt: bf16 (tap,o=128,i=128).
// Block: 256 thr = 4 waves (2M x 2N). Block tile M=128 (all o) x N=64 (one row).
// Wave tile 64x32: mf=4 x nf=2 frags of 16x16, K=9*128 via 36 steps of 32.
// Epilogue: +bias, leaky(0.2), optional +residual(NCHW f32);
// writes f32 NCHW and/or bf16 hwC.
template <int DIL, bool WF32, bool WBF16, bool RES>
__global__ __launch_bounds__(256) void conv_mfma(
    const unsigned short* __restrict__ Xb,
    const unsigned short* __restrict__ Wt,
    const float* __restrict__ Bi,
    const float* __restrict__ Rs,
    float* __restrict__ Yf,
    unsigned short* __restrict__ Ybf) {
  int tid = threadIdx.x;
  int lane = tid & 63, wid = tid >> 6;
  int wm = wid & 1, wn = wid >> 1;
  int ml = lane & 15, kg = lane >> 4;
  int bt = blockIdx.x >> 6, h = blockIdx.x & 63;
  const int wbase = wn * 32;

  f32x4 acc[4][2];
#pragma unroll
  for (int i = 0; i < 4; i++)
#pragma unroll
    for (int j = 0; j < 2; j++)
      acc[i][j] = {0.f, 0.f, 0.f, 0.f};

#pragma unroll
  for (int kh = 0; kh < 3; kh++) {
    int r = h + (kh - 1) * DIL;
    if ((unsigned)r >= 64u) continue;  // wave-uniform row skip
    const unsigned short* Xr = Xb + ((size_t)(bt * 64 + r) << 13);
#pragma unroll
    for (int kw = 0; kw < 3; kw++) {
      const unsigned short* Wp = Wt + (kh * 3 + kw) * 16384;
      int shf = (kw - 1) * DIL;
#pragma unroll
      for (int c = 0; c < 128; c += 32) {
        bf16x8 a[4], b[2];
#pragma unroll
        for (int mf = 0; mf < 4; mf++)
          a[mf] = *(const bf16x8*)(Wp + (wm * 64 + mf * 16 + ml) * 128 + c + kg * 8);
#pragma unroll
        for (int nf = 0; nf < 2; nf++) {
          int wp = wbase + nf * 16 + ml + shf;
          int wpc = wp < 0 ? 0 : (wp > 63 ? 63 : wp);
          bf16x8 t = *(const bf16x8*)(Xr + wpc * 128 + c + kg * 8);
          bf16x8 bz = {0, 0, 0, 0, 0, 0, 0, 0};
          b[nf] = ((unsigned)wp < 64u) ? t : bz;
        }
#pragma unroll
        for (int mf = 0; mf < 4; mf++)
#pragma unroll
          for (int nf = 0; nf < 2; nf++)
            acc[mf][nf] = __builtin_amdgcn_mfma_f32_16x16x32_bf16(
                a[mf], b[nf], acc[mf][nf], 0, 0, 0);
      }
    }
  }

#pragma unroll
  for (int mf = 0; mf < 4; mf++) {
    int obase = wm * 64 + mf * 16 + kg * 4;
#pragma unroll
    for (int nf = 0; nf < 2; nf++) {
      int w = wbase + nf * 16 + ml;
      float v[4];
#pragma unroll
      for (int r4 = 0; r4 < 4; r4++) {
        int o = obase + r4;
        float val = acc[mf][nf][r4] + Bi[o];
        val = val > 0.f ? val : 0.2f * val;
        size_t idx = (((size_t)bt * 128 + o) * 64 + h) * 64 + w;
        if (RES) val += Rs[idx];
        if (WF32) Yf[idx] = val;
        v[r4] = val;
      }
      if (WBF16) {
        unsigned int lo = (unsigned int)f2bf(v[0]) | ((unsigned int)f2bf(v[1]) << 16);
        unsigned int hi = (unsigned int)f2bf(v[2]) | ((unsigned int)f2bf(v[3]) << 16);
        *(uint2*)(Ybf + (((size_t)bt * 4096 + h * 64 + w) * 128 + obase)) =
            make_uint2(lo, hi);
      }
    }
  }
}

extern "C" void kernel_launch(void* const* d_in, const int* in_sizes, int n_in,
                              void* d_out, int out_size, void* d_ws, size_t ws_size,
                              hipStream_t stream) {
  (void)in_sizes; (void)n_in; (void)out_size; (void)ws_size;
  const float* x   = (const float*)d_in[0];
  const float* Wq  = (const float*)d_in[1];
  const float* bq  = (const float*)d_in[2];
  const float* Wk  = (const float*)d_in[3];
  const float* bk  = (const float*)d_in[4];
  const float* Wv  = (const float*)d_in[5];
  const float* bv  = (const float*)d_in[6];
  const float* Wo  = (const float*)d_in[7];
  const float* bo  = (const float*)d_in[8];
  const float* Wf1 = (const float*)d_in[9];
  const float* bf1 = (const float*)d_in[10];
  const float* Wf2 = (const float*)d_in[11];
  const float* bf2 = (const float*)d_in[12];
  float* out = (float*)d_out;

  // workspace layout (~93.7 MB)
  char* wsb = (char*)d_ws;
  float* xcur = (float*)(wsb);                                // 16,777,216
  float* opk  = (float*)(wsb + 16777216);                     // 16,777,216
  float* S1   = (float*)(wsb + 33554432);                     //  8,388,608
  float* S2   = (float*)(wsb + 41943040);                     //    524,288
  float* S3   = (float*)(wsb + 42467328);                     //     32,768
  unsigned short* Qp = (unsigned short*)(wsb + 42500096);     //  8,388,608
  unsigned short* Kp = (unsigned short*)(wsb + 50888704);     //  8,388,608
  unsigned short* Vp = (unsigned short*)(wsb + 59277312);     //  8,388,608
  unsigned short* att_hwc  = (unsigned short*)(wsb + 67665920); // 8,388,608
  unsigned short* xcur_hwc = (unsigned short*)(wsb + 76054528); // 8,388,608
  unsigned short* f1_hwc   = (unsigned short*)(wsb + 84443136); // 8,388,608
  unsigned short* Wt0 = (unsigned short*)(wsb + 92831744);    // 294,912
  unsigned short* Wt1 = (unsigned short*)(wsb + 93126656);    // 294,912
  unsigned short* Wt2 = (unsigned short*)(wsb + 93421568);    // 294,912

  hipMemcpyAsync(xcur, x, 16777216, hipMemcpyDeviceToDevice, stream);

  const int Ls[3] = {1024, 256, 64};
  const int Ds[3] = {512, 2048, 8192};
  float* Sb[3] = {S1, S2, S3};
  dim3 blk(256);

  for (int layer = 0; layer < 2; layer++) {
    const float* wq  = Wq  + layer * 16384;
    const float* wk  = Wk  + layer * 16384;
    const float* wv  = Wv  + layer * 16384;
    const float* bq_ = bq  + layer * 128;
    const float* bk_ = bk  + layer * 128;
    const float* bv_ = bv  + layer * 128;
    const float* wo  = Wo  + layer * 147456;
    const float* bo_ = bo  + layer * 128;
    const float* wf1 = Wf1 + layer * 147456;
    const float* bf1_ = bf1 + layer * 128;
    const float* wf2 = Wf2 + layer * 147456;
    const float* bf2_ = bf2 + layer * 128;

    wprep<<<dim3(576), blk, 0, stream>>>(wo, Wt0);
    wprep<<<dim3(576), blk, 0, stream>>>(wf1, Wt1);
    wprep<<<dim3(576), blk, 0, stream>>>(wf2, Wt2);

    qkv_gemm<<<dim3(256, 8, 8), blk, 0, stream>>>(xcur, wq, bq_, Qp, 1);
    qkv_gemm<<<dim3(256, 8, 8), blk, 0, stream>>>(xcur, wk, bk_, Kp, 0);
    qkv_gemm<<<dim3(256, 8, 8), blk, 0, stream>>>(xcur, wv, bv_, Vp, 0);

    flash_g0<<<dim3(512), blk, 0, stream>>>(Qp, Kp, Vp, opk);

    for (int gg = 0; gg < 3; gg++) {
      int g = gg + 1;
      size_t go = (size_t)g << 20;
      int L = Ls[gg], D = Ds[gg];
      s_gemm<<<dim3(L / 16, L / 16, 2), blk, 0, stream>>>(Qp + go, Kp + go, Sb[gg], L, D);
      softmax_rows<<<dim3(2 * L), blk, 0, stream>>>(Sb[gg], L);
      pv_gemm<<<dim3(D / 16, L / 16, 2), blk, 0, stream>>>(Sb[gg], Vp + go, opk + go, L, D);
    }

    unpack_att_bf16<<<dim3(2048), blk, 0, stream>>>(opk, att_hwc);

    // x = x + leaky(conv1(att));  writes f32 NCHW (xcur) + bf16 hwC
    conv_mfma<1, true, true, true><<<dim3(512), blk, 0, stream>>>(
        att_hwc, Wt0, bo_, xcur, xcur, xcur_hwc);
    // f = leaky(conv_dil2(x));  bf16 hwC only
    conv_mfma<2, false, true, false><<<dim3(512), blk, 0, stream>>>(
        xcur_hwc, Wt1, bf1_, nullptr, nullptr, f1_hwc);
    // y = x + leaky(conv1(f));  f32 NCHW (xcur or out)
    float* dst = (layer == 1) ? out : xcur;
    conv_mfma<1, true, false, true><<<dim3(512), blk, 0, stream>>>(
        f1_hwc, Wt2, bf2_, xcur, dst, nullptr);
  }
}

// Round 4
// 1201.585 us; speedup vs baseline: 6.9796x; 2.1397x over previous
//
#include <hip/hip_runtime.h>

// ---------- bf16 helpers (manual, RNE) ----------
__device__ __forceinline__ unsigned short f2bf(float f) {
  union { float f; unsigned int i; } c; c.f = f;
  unsigned int i = c.i;
  i += 0x7fffu + ((i >> 16) & 1u);
  return (unsigned short)(i >> 16);
}

typedef __attribute__((ext_vector_type(8))) short bf16x8;
typedef __attribute__((ext_vector_type(4))) float f32x4;

// Geometry: x is (bt=8, C=128, 64, 64); bt = b*4 + t (b=2, t=4).
// Head group g (0..3): patch p = 1<<(g+1), dk = 32 channels.
// Packed token layout per group: (b, l, d); L*D = 1<<19; group base = g<<20.
// Vt layout per group: (b, d, l) same base/extent.
// MFMA convention (proven by conv_mfma r2->r3):
//   A-frag: lane(ml=lane&15,kg=lane>>4) holds A[row=ml][c=kg*8+j]
//   B-frag: lane holds B[c=kg*8+j][col=ml]
//   C/D   : lane holds D[row=kg*4+reg][col=ml]

// ---------- x (NCHW f32) -> x_hwc (pix_g, 128) bf16 ----------
__global__ __launch_bounds__(256) void x2hwc(const float* __restrict__ X,
                                             unsigned short* __restrict__ Xh) {
  int pixg = blockIdx.x * 256 + threadIdx.x;  // 32768
  int c0 = blockIdx.y * 8;
  int bt = pixg >> 12, pix = pixg & 4095;
  const float* src = X + ((size_t)bt << 19) + (size_t)c0 * 4096 + pix;
  unsigned int pk[4];
#pragma unroll
  for (int j = 0; j < 4; j++) {
    unsigned short u0 = f2bf(src[(2 * j) * 4096]);
    unsigned short u1 = f2bf(src[(2 * j + 1) * 4096]);
    pk[j] = (unsigned int)u0 | ((unsigned int)u1 << 16);
  }
  *(uint4*)(Xh + (size_t)pixg * 128 + c0) = make_uint4(pk[0], pk[1], pk[2], pk[3]);
}

// ---------- weight prep 3x3: (o,i,3,3) f32 -> (tap,o,i) bf16, 3 at once ----------
__global__ __launch_bounds__(256) void wprep3(
    const float* __restrict__ s0, const float* __restrict__ s1,
    const float* __restrict__ s2, unsigned short* __restrict__ d0,
    unsigned short* __restrict__ d1, unsigned short* __restrict__ d2) {
  int idx = blockIdx.x * 256 + threadIdx.x;  // 147456
  const float* s = blockIdx.y == 0 ? s0 : (blockIdx.y == 1 ? s1 : s2);
  unsigned short* d = blockIdx.y == 0 ? d0 : (blockIdx.y == 1 ? d1 : d2);
  int tap = idx >> 14, rem = idx & 16383;
  int o = rem >> 7, i = rem & 127;
  d[idx] = f2bf(s[(size_t)(o * 128 + i) * 9 + tap]);
}

// ---------- weight prep 1x1: (o,i) f32 -> bf16, 3 at once ----------
__global__ __launch_bounds__(256) void wprep1(
    const float* __restrict__ s0, const float* __restrict__ s1,
    const float* __restrict__ s2, unsigned short* __restrict__ d0,
    unsigned short* __restrict__ d1, unsigned short* __restrict__ d2) {
  int idx = blockIdx.x * 256 + threadIdx.x;  // 16384
  const float* s = blockIdx.y == 0 ? s0 : (blockIdx.y == 1 ? s1 : s2);
  unsigned short* d = blockIdx.y == 0 ? d0 : (blockIdx.y == 1 ? d1 : d2);
  d[idx] = f2bf(s[idx]);
}

// ---------- QKV projection: MFMA GEMM W(128x128) x Xh^T with pack epilogue ----------
// MODE: 0=q (scale), 1=k, 2=v (also writes Vt). grid (512, 2).
template <int MODE>
__global__ __launch_bounds__(256) void qkv_pack(
    const unsigned short* __restrict__ Xh, const unsigned short* __restrict__ Wb,
    const float* __restrict__ Bi, unsigned short* __restrict__ P,
    unsigned short* __restrict__ Vt) {
  int tid = threadIdx.x, lane = tid & 63, wid = tid >> 6;
  int wm = wid & 1, wn = wid >> 1;
  int ml = lane & 15, kg = lane >> 4;
  int m_base = blockIdx.y * 64 + wm * 32;
  int n_base = blockIdx.x * 64 + wn * 32;
  f32x4 acc[2][2];
#pragma unroll
  for (int i = 0; i < 2; i++)
#pragma unroll
    for (int j = 0; j < 2; j++) acc[i][j] = {0.f, 0.f, 0.f, 0.f};
#pragma unroll
  for (int kc = 0; kc < 128; kc += 32) {
    bf16x8 af[2], bf[2];
#pragma unroll
    for (int mf = 0; mf < 2; mf++)
      af[mf] = *(const bf16x8*)(Wb + (size_t)(m_base + mf * 16 + ml) * 128 + kc + kg * 8);
#pragma unroll
    for (int nf = 0; nf < 2; nf++)
      bf[nf] = *(const bf16x8*)(Xh + (size_t)(n_base + nf * 16 + ml) * 128 + kc + kg * 8);
#pragma unroll
    for (int mf = 0; mf < 2; mf++)
#pragma unroll
      for (int nf = 0; nf < 2; nf++)
        acc[mf][nf] = __builtin_amdgcn_mfma_f32_16x16x32_bf16(af[mf], bf[nf], acc[mf][nf], 0, 0, 0);
  }
#pragma unroll
  for (int mf = 0; mf < 2; mf++)
#pragma unroll
    for (int nf = 0; nf < 2; nf++)
#pragma unroll
      for (int r = 0; r < 4; r++) {
        int c = m_base + mf * 16 + kg * 4 + r;
        int pixg = n_base + nf * 16 + ml;
        float val = acc[mf][nf][r] + Bi[c];
        int bt = pixg >> 12, pix = pixg & 4095;
        int h = pix >> 6, w = pix & 63;
        int g = c >> 5, sh = g + 1, msk = (1 << sh) - 1, ohn = 64 >> sh;
        int b = bt >> 2, t_i = bt & 3;
        int l = (t_i * ohn + (h >> sh)) * ohn + (w >> sh);
        int Dg = 32 << (2 * sh);
        int d = ((c & 31) << (2 * sh)) + ((h & msk) << sh) + (w & msk);
        if (MODE == 0) val *= rsqrtf((float)Dg);
        size_t base = ((size_t)g << 20) + ((size_t)b << 19);
        unsigned short bv = f2bf(val);
        P[base + (size_t)l * Dg + d] = bv;
        if (MODE == 2) {
          int Lg = 16384 >> (2 * sh);
          Vt[base + (size_t)d * Lg + l] = bv;
        }
      }
}

// ---------- generic MFMA GEMM: C(MxN) f32 = A(MxK) * B(NxK)^T, bf16 ----------
// grid (N/64, M/64, batch). Both operands K-contiguous row-major.
__global__ __launch_bounds__(256) void gemm_tn(
    const unsigned short* __restrict__ A, const unsigned short* __restrict__ B,
    float* __restrict__ C, int K, int lda, int ldb, int ldc,
    long long sA, long long sB, long long sC) {
  int tid = threadIdx.x, lane = tid & 63, wid = tid >> 6;
  int wm = wid & 1, wn = wid >> 1;
  int ml = lane & 15, kg = lane >> 4;
  A += (size_t)blockIdx.z * sA;
  B += (size_t)blockIdx.z * sB;
  C += (size_t)blockIdx.z * sC;
  int m_base = blockIdx.y * 64 + wm * 32;
  int n_base = blockIdx.x * 64 + wn * 32;
  f32x4 acc[2][2];
#pragma unroll
  for (int i = 0; i < 2; i++)
#pragma unroll
    for (int j = 0; j < 2; j++) acc[i][j] = {0.f, 0.f, 0.f, 0.f};
  for (int kc = 0; kc < K; kc += 32) {
    bf16x8 af[2], bf[2];
#pragma unroll
    for (int mf = 0; mf < 2; mf++)
      af[mf] = *(const bf16x8*)(A + (size_t)(m_base + mf * 16 + ml) * lda + kc + kg * 8);
#pragma unroll
    for (int nf = 0; nf < 2; nf++)
      bf[nf] = *(const bf16x8*)(B + (size_t)(n_base + nf * 16 + ml) * ldb + kc + kg * 8);
#pragma unroll
    for (int mf = 0; mf < 2; mf++)
#pragma unroll
      for (int nf = 0; nf < 2; nf++)
        acc[mf][nf] = __builtin_amdgcn_mfma_f32_16x16x32_bf16(af[mf], bf[nf], acc[mf][nf], 0, 0, 0);
  }
#pragma unroll
  for (int mf = 0; mf < 2; mf++)
#pragma unroll
    for (int nf = 0; nf < 2; nf++)
#pragma unroll
      for (int r = 0; r < 4; r++) {
        int m = m_base + mf * 16 + kg * 4 + r;
        int n = n_base + nf * 16 + ml;
        C[(size_t)m * ldc + n] = acc[mf][nf][r];
      }
}

// ---------- row softmax f32 -> bf16 ----------
__global__ __launch_bounds__(256) void softmax_bf16(float* __restrict__ S,
                                                    unsigned short* __restrict__ P, int L) {
  __shared__ float red[256];
  int tid = threadIdx.x;
  float* p = S + (size_t)blockIdx.x * L;
  unsigned short* o = P + (size_t)blockIdx.x * L;
  float mx = -1e30f;
  for (int e = tid; e < L; e += 256) mx = fmaxf(mx, p[e]);
  red[tid] = mx; __syncthreads();
  for (int s = 128; s > 0; s >>= 1) {
    if (tid < s) red[tid] = fmaxf(red[tid], red[tid + s]);
    __syncthreads();
  }
  mx = red[0]; __syncthreads();
  float sm = 0.f;
  for (int e = tid; e < L; e += 256) {
    float v = __expf(p[e] - mx);
    p[e] = v; sm += v;
  }
  red[tid] = sm; __syncthreads();
  for (int s = 128; s > 0; s >>= 1) {
    if (tid < s) red[tid] += red[tid + s];
    __syncthreads();
  }
  float inv = 1.f / red[0];
  for (int e = tid; e < L; e += 256) o[e] = f2bf(p[e] * inv);
}

// ---------- MFMA flash attention for group 0 (L=4096, D=128) ----------
// grid 512: b = bid>>8, qtile(16 q) = bid&255. 4 waves = 4-way K-split (1024 keys each).
__global__ __launch_bounds__(256) void flash_mfma(
    const unsigned short* __restrict__ Q, const unsigned short* __restrict__ K,
    const unsigned short* __restrict__ Vt, float* __restrict__ O) {
  __shared__ float Ot[4][16][128];
  __shared__ unsigned short Pl[4][16][72];
  __shared__ float Ml[4][16], Ll[4][16];
  int tid = threadIdx.x, lane = tid & 63, wv = tid >> 6;
  int ml = lane & 15, kg = lane >> 4;
  int b = blockIdx.x >> 8, qt = blockIdx.x & 255;
  size_t bofs = (size_t)b << 19;
  int q0 = qt * 16;
  const unsigned short* Qb = Q + bofs;
  const unsigned short* Kb = K + bofs;
  const unsigned short* Vb = Vt + bofs;

  bf16x8 qf[4];
#pragma unroll
  for (int cc = 0; cc < 4; cc++)
    qf[cc] = *(const bf16x8*)(Qb + (size_t)(q0 + ml) * 128 + cc * 32 + kg * 8);

  float m_i = -1e30f, l_i = 0.f;
  f32x4 of[8];
#pragma unroll
  for (int nf = 0; nf < 8; nf++) of[nf] = {0.f, 0.f, 0.f, 0.f};

  for (int k0 = wv * 1024; k0 < wv * 1024 + 1024; k0 += 64) {
    // S^T = K x Q  (D[row=key-local][col=q])
    f32x4 st[4];
#pragma unroll
    for (int mf = 0; mf < 4; mf++) st[mf] = {0.f, 0.f, 0.f, 0.f};
#pragma unroll
    for (int cc = 0; cc < 4; cc++) {
#pragma unroll
      for (int mf = 0; mf < 4; mf++) {
        bf16x8 kf = *(const bf16x8*)(Kb + (size_t)(k0 + mf * 16 + ml) * 128 + cc * 32 + kg * 8);
        st[mf] = __builtin_amdgcn_mfma_f32_16x16x32_bf16(kf, qf[cc], st[mf], 0, 0, 0);
      }
    }
    // online softmax for q = ml
    float cmax = -1e30f;
#pragma unroll
    for (int mf = 0; mf < 4; mf++)
#pragma unroll
      for (int r = 0; r < 4; r++) cmax = fmaxf(cmax, st[mf][r]);
    cmax = fmaxf(cmax, __shfl_xor(cmax, 16));
    cmax = fmaxf(cmax, __shfl_xor(cmax, 32));
    float mnew = fmaxf(m_i, cmax);
    float alpha = __expf(m_i - mnew);
    float p[4][4];
    float psum = 0.f;
#pragma unroll
    for (int mf = 0; mf < 4; mf++)
#pragma unroll
      for (int r = 0; r < 4; r++) {
        float pv = __expf(st[mf][r] - mnew);
        p[mf][r] = pv; psum += pv;
      }
    psum += __shfl_xor(psum, 16);
    psum += __shfl_xor(psum, 32);
    l_i = l_i * alpha + psum;
    m_i = mnew;
    // rescale O (rows q = kg*4+r need alpha from lane ml=kg*4+r)
    float a0 = __shfl(alpha, kg * 4 + 0), a1 = __shfl(alpha, kg * 4 + 1);
    float a2 = __shfl(alpha, kg * 4 + 2), a3 = __shfl(alpha, kg * 4 + 3);
#pragma unroll
    for (int nf = 0; nf < 8; nf++) {
      of[nf][0] *= a0; of[nf][1] *= a1; of[nf][2] *= a2; of[nf][3] *= a3;
    }
    // P -> per-wave LDS (bf16), rows = q
#pragma unroll
    for (int mf = 0; mf < 4; mf++) {
      unsigned int lo = (unsigned int)f2bf(p[mf][0]) | ((unsigned int)f2bf(p[mf][1]) << 16);
      unsigned int hi = (unsigned int)f2bf(p[mf][2]) | ((unsigned int)f2bf(p[mf][3]) << 16);
      *(uint2*)&Pl[wv][ml][mf * 16 + kg * 4] = make_uint2(lo, hi);
    }
    bf16x8 pa0 = *(const bf16x8*)&Pl[wv][ml][kg * 8];
    bf16x8 pa1 = *(const bf16x8*)&Pl[wv][ml][32 + kg * 8];
    // O += P x V  (B-frag from Vt rows = d)
#pragma unroll
    for (int nf = 0; nf < 8; nf++) {
      bf16x8 v0 = *(const bf16x8*)(Vb + (size_t)(nf * 16 + ml) * 4096 + k0 + kg * 8);
      bf16x8 v1 = *(const bf16x8*)(Vb + (size_t)(nf * 16 + ml) * 4096 + k0 + 32 + kg * 8);
      of[nf] = __builtin_amdgcn_mfma_f32_16x16x32_bf16(pa0, v0, of[nf], 0, 0, 0);
      of[nf] = __builtin_amdgcn_mfma_f32_16x16x32_bf16(pa1, v1, of[nf], 0, 0, 0);
    }
  }

  // merge 4 K-splits
  if (kg == 0) { Ml[wv][ml] = m_i; Ll[wv][ml] = l_i; }
  __syncthreads();
  float m0 = Ml[0][ml], m1 = Ml[1][ml], m2 = Ml[2][ml], m3 = Ml[3][ml];
  float mt = fmaxf(fmaxf(m0, m1), fmaxf(m2, m3));
  float lt = Ll[0][ml] * __expf(m0 - mt) + Ll[1][ml] * __expf(m1 - mt) +
             Ll[2][ml] * __expf(m2 - mt) + Ll[3][ml] * __expf(m3 - mt);
  float s = __expf(m_i - mt) / lt;  // per q=ml, includes final 1/l
  float s0 = __shfl(s, kg * 4 + 0), s1 = __shfl(s, kg * 4 + 1);
  float s2 = __shfl(s, kg * 4 + 2), s3 = __shfl(s, kg * 4 + 3);
#pragma unroll
  for (int nf = 0; nf < 8; nf++) {
    Ot[wv][kg * 4 + 0][nf * 16 + ml] = of[nf][0] * s0;
    Ot[wv][kg * 4 + 1][nf * 16 + ml] = of[nf][1] * s1;
    Ot[wv][kg * 4 + 2][nf * 16 + ml] = of[nf][2] * s2;
    Ot[wv][kg * 4 + 3][nf * 16 + ml] = of[nf][3] * s3;
  }
  __syncthreads();
  int base = tid * 8;
  int q = base >> 7, d = base & 127;
  float4 r0 = make_float4(0, 0, 0, 0), r1 = make_float4(0, 0, 0, 0);
#pragma unroll
  for (int w = 0; w < 4; w++) {
    float4 a = *(const float4*)&Ot[w][q][d];
    float4 c = *(const float4*)&Ot[w][q][d + 4];
    r0.x += a.x; r0.y += a.y; r0.z += a.z; r0.w += a.w;
    r1.x += c.x; r1.y += c.y; r1.z += c.z; r1.w += c.w;
  }
  float* Op = O + bofs + (size_t)(q0 + q) * 128 + d;
  *(float4*)Op = r0;
  *(float4*)(Op + 4) = r1;
}

// ---------- unpack packed attention output to bf16 (bt,h,w,C) ----------
__global__ __launch_bounds__(256) void unpack_att_bf16(
    const float* __restrict__ opk, unsigned short* __restrict__ att) {
  int idx = blockIdx.x * 256 + threadIdx.x;
  int oct = idx & 15, pix = idx >> 4;
  int w = pix & 63, h = (pix >> 6) & 63, bt = pix >> 12;
  int c0 = oct * 8;
  int g = c0 >> 5;
  int sh = g + 1, msk = (1 << sh) - 1;
  int ohn = 64 >> sh;
  int b = bt >> 2, t_i = bt & 3;
  int l = (t_i * ohn + (h >> sh)) * ohn + (w >> sh);
  int Dg = 32 << (2 * sh);
  int dbase = ((c0 & 31) << (2 * sh)) + ((h & msk) << sh) + (w & msk);
  const float* src = opk + ((size_t)g << 20) + ((size_t)b << 19) + (size_t)l * Dg;
  int dstep = 1 << (2 * sh);
  unsigned int pk[4];
#pragma unroll
  for (int j = 0; j < 4; j++) {
    unsigned short u0 = f2bf(src[dbase + (2 * j) * dstep]);
    unsigned short u1 = f2bf(src[dbase + (2 * j + 1) * dstep]);
    pk[j] = (unsigned int)u0 | ((unsigned int)u1 << 16);
  }
  *(uint4*)(att + ((size_t)pix * 128 + c0)) = make_uint4(pk[0], pk[1], pk[2], pk[3]);
}

// ---------- MFMA implicit-GEMM 3x3 conv (LDS-free, direct global frags) ----------
template <int DIL, bool WF32, bool WBF16, bool RES>
__global__ __launch_bounds__(256) void conv_mfma(
    const unsigned short* __restrict__ Xb,
    const unsigned short* __restrict__ Wt,
    const float* __restrict__ Bi,
    const float* __restrict__ Rs,
    float* __restrict__ Yf,
    unsigned short* __restrict__ Ybf) {
  int tid = threadIdx.x;
  int lane = tid & 63, wid = tid >> 6;
  int wm = wid & 1, wn = wid >> 1;
  int ml = lane & 15, kg = lane >> 4;
  int bt = blockIdx.x >> 6, h = blockIdx.x & 63;
  const int wbase = wn * 32;

  f32x4 acc[4][2];
#pragma unroll
  for (int i = 0; i < 4; i++)
#pragma unroll
    for (int j = 0; j < 2; j++)
      acc[i][j] = {0.f, 0.f, 0.f, 0.f};

#pragma unroll
  for (int kh = 0; kh < 3; kh++) {
    int r = h + (kh - 1) * DIL;
    if ((unsigned)r >= 64u) continue;
    const unsigned short* Xr = Xb + ((size_t)(bt * 64 + r) << 13);
#pragma unroll
    for (int kw = 0; kw < 3; kw++) {
      const unsigned short* Wp = Wt + (kh * 3 + kw) * 16384;
      int shf = (kw - 1) * DIL;
#pragma unroll
      for (int c = 0; c < 128; c += 32) {
        bf16x8 a[4], b[2];
#pragma unroll
        for (int mf = 0; mf < 4; mf++)
          a[mf] = *(const bf16x8*)(Wp + (wm * 64 + mf * 16 + ml) * 128 + c + kg * 8);
#pragma unroll
        for (int nf = 0; nf < 2; nf++) {
          int wp = wbase + nf * 16 + ml + shf;
          int wpc = wp < 0 ? 0 : (wp > 63 ? 63 : wp);
          bf16x8 t = *(const bf16x8*)(Xr + wpc * 128 + c + kg * 8);
          bf16x8 bz = {0, 0, 0, 0, 0, 0, 0, 0};
          b[nf] = ((unsigned)wp < 64u) ? t : bz;
        }
#pragma unroll
        for (int mf = 0; mf < 4; mf++)
#pragma unroll
          for (int nf = 0; nf < 2; nf++)
            acc[mf][nf] = __builtin_amdgcn_mfma_f32_16x16x32_bf16(
                a[mf], b[nf], acc[mf][nf], 0, 0, 0);
      }
    }
  }

#pragma unroll
  for (int mf = 0; mf < 4; mf++) {
    int obase = wm * 64 + mf * 16 + kg * 4;
#pragma unroll
    for (int nf = 0; nf < 2; nf++) {
      int w = wbase + nf * 16 + ml;
      float v[4];
#pragma unroll
      for (int r4 = 0; r4 < 4; r4++) {
        int o = obase + r4;
        float val = acc[mf][nf][r4] + Bi[o];
        val = val > 0.f ? val : 0.2f * val;
        size_t idx = (((size_t)bt * 128 + o) * 64 + h) * 64 + w;
        if (RES) val += Rs[idx];
        if (WF32) Yf[idx] = val;
        v[r4] = val;
      }
      if (WBF16) {
        unsigned int lo = (unsigned int)f2bf(v[0]) | ((unsigned int)f2bf(v[1]) << 16);
        unsigned int hi = (unsigned int)f2bf(v[2]) | ((unsigned int)f2bf(v[3]) << 16);
        *(uint2*)(Ybf + (((size_t)bt * 4096 + h * 64 + w) * 128 + obase)) =
            make_uint2(lo, hi);
      }
    }
  }
}

extern "C" void kernel_launch(void* const* d_in, const int* in_sizes, int n_in,
                              void* d_out, int out_size, void* d_ws, size_t ws_size,
                              hipStream_t stream) {
  (void)in_sizes; (void)n_in; (void)out_size; (void)ws_size;
  const float* x   = (const float*)d_in[0];
  const float* Wq  = (const float*)d_in[1];
  const float* bq  = (const float*)d_in[2];
  const float* Wk  = (const float*)d_in[3];
  const float* bk  = (const float*)d_in[4];
  const float* Wv  = (const float*)d_in[5];
  const float* bv  = (const float*)d_in[6];
  const float* Wo  = (const float*)d_in[7];
  const float* bo  = (const float*)d_in[8];
  const float* Wf1 = (const float*)d_in[9];
  const float* bf1 = (const float*)d_in[10];
  const float* Wf2 = (const float*)d_in[11];
  const float* bf2 = (const float*)d_in[12];
  float* out = (float*)d_out;

  // workspace layout (93,257,728 B total)
  char* wsb = (char*)d_ws;
  float* xcur = (float*)(wsb);                                  // 16 MB
  float* opk  = (float*)(wsb + 16777216);                       // 16 MB
  float* S    = (float*)(wsb + 33554432);                       //  8 MB
  unsigned short* Qp = (unsigned short*)(wsb + 41943040);       //  8 MB
  unsigned short* Kp = (unsigned short*)(wsb + 50331648);       //  8 MB
  unsigned short* Vp = (unsigned short*)(wsb + 58720256);       //  8 MB
  unsigned short* Vt = (unsigned short*)(wsb + 67108864);       //  8 MB
  unsigned short* att_hwc  = (unsigned short*)(wsb + 75497472); //  8 MB (also f1_hwc)
  unsigned short* xcur_hwc = (unsigned short*)(wsb + 83886080); //  8 MB (also Pb)
  unsigned short* Wt0 = (unsigned short*)(wsb + 92274688);
  unsigned short* Wt1 = (unsigned short*)(wsb + 92569600);
  unsigned short* Wt2 = (unsigned short*)(wsb + 92864512);
  unsigned short* Wqb = (unsigned short*)(wsb + 93159424);
  unsigned short* Wkb = (unsigned short*)(wsb + 93192192);
  unsigned short* Wvb = (unsigned short*)(wsb + 93224960);
  unsigned short* f1_hwc = att_hwc;
  unsigned short* Pb = xcur_hwc;

  hipMemcpyAsync(xcur, x, 16777216, hipMemcpyDeviceToDevice, stream);

  const int Ls[3] = {1024, 256, 64};
  const int Ds[3] = {512, 2048, 8192};
  dim3 blk(256);

  x2hwc<<<dim3(128, 16), blk, 0, stream>>>(x, xcur_hwc);

  for (int layer = 0; layer < 2; layer++) {
    const float* wq  = Wq  + layer * 16384;
    const float* wk  = Wk  + layer * 16384;
    const float* wv  = Wv  + layer * 16384;
    const float* bq_ = bq  + layer * 128;
    const float* bk_ = bk  + layer * 128;
    const float* bv_ = bv  + layer * 128;
    const float* wo  = Wo  + layer * 147456;
    const float* bo_ = bo  + layer * 128;
    const float* wf1 = Wf1 + layer * 147456;
    const float* bf1_ = bf1 + layer * 128;
    const float* wf2 = Wf2 + layer * 147456;
    const float* bf2_ = bf2 + layer * 128;

    wprep3<<<dim3(576, 3), blk, 0, stream>>>(wo, wf1, wf2, Wt0, Wt1, Wt2);
    wprep1<<<dim3(64, 3), blk, 0, stream>>>(wq, wk, wv, Wqb, Wkb, Wvb);

    qkv_pack<0><<<dim3(512, 2), blk, 0, stream>>>(xcur_hwc, Wqb, bq_, Qp, nullptr);
    qkv_pack<1><<<dim3(512, 2), blk, 0, stream>>>(xcur_hwc, Wkb, bk_, Kp, nullptr);
    qkv_pack<2><<<dim3(512, 2), blk, 0, stream>>>(xcur_hwc, Wvb, bv_, Vp, Vt);

    flash_mfma<<<dim3(512), blk, 0, stream>>>(Qp, Kp, Vt, opk);

    for (int gg = 0; gg < 3; gg++) {
      int g = gg + 1;
      size_t go = (size_t)g << 20;
      int L = Ls[gg], D = Ds[gg];
      gemm_tn<<<dim3(L / 64, L / 64, 2), blk, 0, stream>>>(
          Qp + go, Kp + go, S, D, D, D, L, 1LL << 19, 1LL << 19, (long long)L * L);
      softmax_bf16<<<dim3(2 * L), blk, 0, stream>>>(S, Pb, L);
      gemm_tn<<<dim3(D / 64, L / 64, 2), blk, 0, stream>>>(
          Pb, Vt + go, opk + go, L, L, L, D, (long long)L * L, 1LL << 19, 1LL << 19);
    }

    unpack_att_bf16<<<dim3(2048), blk, 0, stream>>>(opk, att_hwc);

    // x = x + leaky(conv1(att))
    conv_mfma<1, true, true, true><<<dim3(512), blk, 0, stream>>>(
        att_hwc, Wt0, bo_, xcur, xcur, xcur_hwc);
    // f = leaky(conv_dil2(x))
    conv_mfma<2, false, true, false><<<dim3(512), blk, 0, stream>>>(
        xcur_hwc, Wt1, bf1_, nullptr, nullptr, f1_hwc);
    // y = x + leaky(conv1(f))
    if (layer == 0) {
      conv_mfma<1, true, true, true><<<dim3(512), blk, 0, stream>>>(
          f1_hwc, Wt2, bf2_, xcur, xcur, xcur_hwc);
    } else {
      conv_mfma<1, true, false, true><<<dim3(512), blk, 0, stream>>>(
          f1_hwc, Wt2, bf2_, xcur, out, nullptr);
    }
  }
}

// Round 6
// 857.785 us; speedup vs baseline: 9.7770x; 1.4008x over previous
//
#include <hip/hip_runtime.h>

// ---------- bf16 helpers (manual, RNE) ----------
__device__ __forceinline__ unsigned short f2bf(float f) {
  union { float f; unsigned int i; } c; c.f = f;
  unsigned int i = c.i;
  i += 0x7fffu + ((i >> 16) & 1u);
  return (unsigned short)(i >> 16);
}

typedef __attribute__((ext_vector_type(8))) short bf16x8;
typedef __attribute__((ext_vector_type(4))) float f32x4;

// Geometry: x is (bt=8, C=128, 64, 64); bt = b*4 + t (b=2, t=4).
// Head group g (0..3): patch p = 1<<(g+1), dk = 32 channels.
// Packed token layout per group: (b, l, d); L*D = 1<<19; group base = g<<20.
// MFMA convention (verified):
//   A-frag: lane(ml=lane&15,kg=lane>>4) holds A[row=ml][c=kg*8+j]
//   B-frag: lane holds B[c=kg*8+j][col=ml]
//   C/D   : lane holds D[row=kg*4+reg][col=ml]
// g0 fragment-major layouts (contiguous 1KB per wave frag-load):
//   Qf[b][qt][cc4][lane64][8]   element (q=qt*16+ml, d=cc*32+kg*8+j)
//   Kf[b][ck64][cc4][mf4][lane64][8]  (key=ck*64+mf*16+ml, d=cc*32+kg*8+j)
//   Vf[b][ck64][nf8][part2][lane64][8] (key=ck*64+part*32+kg*8+j, d=nf*16+ml)

// ---------- x (NCHW f32) -> x_hwc (pix_g, 128) bf16 ----------
__global__ __launch_bounds__(256) void x2hwc(const float* __restrict__ X,
                                             unsigned short* __restrict__ Xh) {
  int pixg = blockIdx.x * 256 + threadIdx.x;  // 32768
  int c0 = blockIdx.y * 8;
  int bt = pixg >> 12, pix = pixg & 4095;
  const float* src = X + ((size_t)bt << 19) + (size_t)c0 * 4096 + pix;
  unsigned int pk[4];
#pragma unroll
  for (int j = 0; j < 4; j++) {
    unsigned short u0 = f2bf(src[(2 * j) * 4096]);
    unsigned short u1 = f2bf(src[(2 * j + 1) * 4096]);
    pk[j] = (unsigned int)u0 | ((unsigned int)u1 << 16);
  }
  *(uint4*)(Xh + (size_t)pixg * 128 + c0) = make_uint4(pk[0], pk[1], pk[2], pk[3]);
}

// ---------- weight prep 3x3: (o,i,3,3) f32 -> fragment-major bf16 ----------
// out idx: [tap9][cs4][wm2][mf4][lane64][j8]; o=wm*64+mf*16+ml, i=cs*32+kg*8+j
__global__ __launch_bounds__(256) void wprep3(
    const float* __restrict__ s0, const float* __restrict__ s1,
    const float* __restrict__ s2, unsigned short* __restrict__ d0,
    unsigned short* __restrict__ d1, unsigned short* __restrict__ d2) {
  int idx = blockIdx.x * 256 + threadIdx.x;  // 147456
  const float* s = blockIdx.y == 0 ? s0 : (blockIdx.y == 1 ? s1 : s2);
  unsigned short* d = blockIdx.y == 0 ? d0 : (blockIdx.y == 1 ? d1 : d2);
  int j = idx & 7;
  int lane = (idx >> 3) & 63;
  int kg = lane >> 4, ml = lane & 15;
  int f = idx >> 9;
  int mf = f & 3, wm = (f >> 2) & 1, cs = (f >> 3) & 3, tap = f >> 5;
  int o = wm * 64 + mf * 16 + ml;
  int i = cs * 32 + kg * 8 + j;
  d[idx] = f2bf(s[(size_t)(o * 128 + i) * 9 + tap]);
}

// ---------- weight prep 1x1 ----------
__global__ __launch_bounds__(256) void wprep1(
    const float* __restrict__ s0, const float* __restrict__ s1,
    const float* __restrict__ s2, unsigned short* __restrict__ d0,
    unsigned short* __restrict__ d1, unsigned short* __restrict__ d2) {
  int idx = blockIdx.x * 256 + threadIdx.x;  // 16384
  const float* s = blockIdx.y == 0 ? s0 : (blockIdx.y == 1 ? s1 : s2);
  unsigned short* d = blockIdx.y == 0 ? d0 : (blockIdx.y == 1 ? d1 : d2);
  d[idx] = f2bf(s[idx]);
}

// ---------- QKV projection MFMA GEMM with pack epilogue ----------
// MODE 0=q, 1=k, 2=v. g0 -> fragment-major Ff; g1-3 -> packed P (q,k) / Vt (v).
template <int MODE>
__global__ __launch_bounds__(256) void qkv_pack(
    const unsigned short* __restrict__ Xh, const unsigned short* __restrict__ Wb,
    const float* __restrict__ Bi, unsigned short* __restrict__ P,
    unsigned short* __restrict__ VtP, unsigned short* __restrict__ Ff) {
  int tid = threadIdx.x, lane = tid & 63, wid = tid >> 6;
  int wm = wid & 1, wn = wid >> 1;
  int ml = lane & 15, kg = lane >> 4;
  int m_base = blockIdx.y * 64 + wm * 32;
  int n_base = blockIdx.x * 64 + wn * 32;
  f32x4 acc[2][2];
#pragma unroll
  for (int i = 0; i < 2; i++)
#pragma unroll
    for (int j = 0; j < 2; j++) acc[i][j] = {0.f, 0.f, 0.f, 0.f};
#pragma unroll
  for (int kc = 0; kc < 128; kc += 32) {
    bf16x8 af[2], bfr[2];
#pragma unroll
    for (int mf = 0; mf < 2; mf++)
      af[mf] = *(const bf16x8*)(Wb + (size_t)(m_base + mf * 16 + ml) * 128 + kc + kg * 8);
#pragma unroll
    for (int nf = 0; nf < 2; nf++)
      bfr[nf] = *(const bf16x8*)(Xh + (size_t)(n_base + nf * 16 + ml) * 128 + kc + kg * 8);
#pragma unroll
    for (int mf = 0; mf < 2; mf++)
#pragma unroll
      for (int nf = 0; nf < 2; nf++)
        acc[mf][nf] = __builtin_amdgcn_mfma_f32_16x16x32_bf16(af[mf], bfr[nf], acc[mf][nf], 0, 0, 0);
  }
#pragma unroll
  for (int mf = 0; mf < 2; mf++)
#pragma unroll
    for (int nf = 0; nf < 2; nf++)
#pragma unroll
      for (int r = 0; r < 4; r++) {
        int c = m_base + mf * 16 + kg * 4 + r;
        int pixg = n_base + nf * 16 + ml;
        float val = acc[mf][nf][r] + Bi[c];
        int bt = pixg >> 12, pix = pixg & 4095;
        int h = pix >> 6, w = pix & 63;
        int g = c >> 5, sh = g + 1, msk = (1 << sh) - 1, ohn = 64 >> sh;
        int b = bt >> 2, t_i = bt & 3;
        int l = (t_i * ohn + (h >> sh)) * ohn + (w >> sh);
        int Dg = 32 << (2 * sh);
        int d = ((c & 31) << (2 * sh)) + ((h & msk) << sh) + (w & msk);
        if (MODE == 0) val *= rsqrtf((float)Dg);
        unsigned short bv = f2bf(val);
        size_t bofs = (size_t)b << 19;
        if (g == 0) {
          if (MODE == 0) {
            int qt = l >> 4, mlq = l & 15, cc = d >> 5, kgq = (d >> 3) & 3, j = d & 7;
            Ff[bofs + ((size_t)(qt * 4 + cc) << 9) + (kgq * 16 + mlq) * 8 + j] = bv;
          } else if (MODE == 1) {
            int ck = l >> 6, mfk = (l >> 4) & 3, mlk = l & 15;
            int cc = d >> 5, kgk = (d >> 3) & 3, j = d & 7;
            Ff[bofs + ((size_t)(ck * 16 + cc * 4 + mfk) << 9) + (kgk * 16 + mlk) * 8 + j] = bv;
          } else {
            int ck = l >> 6, part = (l >> 5) & 1, kgv = (l >> 3) & 3, j = l & 7;
            int nf = d >> 4, mlv = d & 15;
            Ff[bofs + ((size_t)(ck * 16 + nf * 2 + part) << 9) + (kgv * 16 + mlv) * 8 + j] = bv;
          }
        } else {
          size_t base = ((size_t)g << 20) + bofs;
          if (MODE != 2) {
            P[base + (size_t)l * Dg + d] = bv;
          } else {
            int Lg = 16384 >> (2 * sh);
            VtP[base + (size_t)d * Lg + l] = bv;
          }
        }
      }
}

// ---------- generic MFMA GEMM: C(MxN) f32 = A(MxK) * B(NxK)^T, bf16 ----------
__global__ __launch_bounds__(256) void gemm_tn(
    const unsigned short* __restrict__ A, const unsigned short* __restrict__ B,
    float* __restrict__ C, int K, int lda, int ldb, int ldc,
    long long sA, long long sB, long long sC) {
  int tid = threadIdx.x, lane = tid & 63, wid = tid >> 6;
  int wm = wid & 1, wn = wid >> 1;
  int ml = lane & 15, kg = lane >> 4;
  A += (size_t)blockIdx.z * sA;
  B += (size_t)blockIdx.z * sB;
  C += (size_t)blockIdx.z * sC;
  int m_base = blockIdx.y * 64 + wm * 32;
  int n_base = blockIdx.x * 64 + wn * 32;
  f32x4 acc[2][2];
#pragma unroll
  for (int i = 0; i < 2; i++)
#pragma unroll
    for (int j = 0; j < 2; j++) acc[i][j] = {0.f, 0.f, 0.f, 0.f};
  for (int kc = 0; kc < K; kc += 32) {
    bf16x8 af[2], bfr[2];
#pragma unroll
    for (int mf = 0; mf < 2; mf++)
      af[mf] = *(const bf16x8*)(A + (size_t)(m_base + mf * 16 + ml) * lda + kc + kg * 8);
#pragma unroll
    for (int nf = 0; nf < 2; nf++)
      bfr[nf] = *(const bf16x8*)(B + (size_t)(n_base + nf * 16 + ml) * ldb + kc + kg * 8);
#pragma unroll
    for (int mf = 0; mf < 2; mf++)
#pragma unroll
      for (int nf = 0; nf < 2; nf++)
        acc[mf][nf] = __builtin_amdgcn_mfma_f32_16x16x32_bf16(af[mf], bfr[nf], acc[mf][nf], 0, 0, 0);
  }
#pragma unroll
  for (int mf = 0; mf < 2; mf++)
#pragma unroll
    for (int nf = 0; nf < 2; nf++)
#pragma unroll
      for (int r = 0; r < 4; r++) {
        int m = m_base + mf * 16 + kg * 4 + r;
        int n = n_base + nf * 16 + ml;
        C[(size_t)m * ldc + n] = acc[mf][nf][r];
      }
}

// ---------- row softmax f32 -> bf16 ----------
__global__ __launch_bounds__(256) void softmax_bf16(float* __restrict__ S,
                                                    unsigned short* __restrict__ P, int L) {
  __shared__ float red[256];
  int tid = threadIdx.x;
  float* p = S + (size_t)blockIdx.x * L;
  unsigned short* o = P + (size_t)blockIdx.x * L;
  float mx = -1e30f;
  for (int e = tid; e < L; e += 256) mx = fmaxf(mx, p[e]);
  red[tid] = mx; __syncthreads();
  for (int s = 128; s > 0; s >>= 1) {
    if (tid < s) red[tid] = fmaxf(red[tid], red[tid + s]);
    __syncthreads();
  }
  mx = red[0]; __syncthreads();
  float sm = 0.f;
  for (int e = tid; e < L; e += 256) {
    float v = __expf(p[e] - mx);
    p[e] = v; sm += v;
  }
  red[tid] = sm; __syncthreads();
  for (int s = 128; s > 0; s >>= 1) {
    if (tid < s) red[tid] += red[tid + s];
    __syncthreads();
  }
  float inv = 1.f / red[0];
  for (int e = tid; e < L; e += 256) o[e] = f2bf(p[e] * inv);
}

// ---------- MFMA flash attention group 0 (L=4096, D=128), frag-major inputs ----------
__global__ __launch_bounds__(256, 2) void flash_mfma(
    const unsigned short* __restrict__ Qf, const unsigned short* __restrict__ Kf,
    const unsigned short* __restrict__ Vf, float* __restrict__ O) {
  __shared__ float Ot[4][16][128];
  __shared__ unsigned short Pl[4][16][72];
  __shared__ float Ml[4][16], Ll[4][16];
  int tid = threadIdx.x, lane = tid & 63, wv = tid >> 6;
  int ml = lane & 15, kg = lane >> 4;
  int b = blockIdx.x >> 8, qt = blockIdx.x & 255;
  size_t bofs = (size_t)b << 19;
  int q0 = qt * 16;

  bf16x8 qf[4];
#pragma unroll
  for (int cc = 0; cc < 4; cc++)
    qf[cc] = *(const bf16x8*)(Qf + bofs + ((size_t)(qt * 4 + cc) << 9) + lane * 8);

  float m_i = -1e30f, l_i = 0.f;
  f32x4 of[8];
#pragma unroll
  for (int nf = 0; nf < 8; nf++) of[nf] = {0.f, 0.f, 0.f, 0.f};

  for (int ck = wv * 16; ck < wv * 16 + 16; ck++) {
    const unsigned short* Kc = Kf + bofs + ((size_t)ck << 13);
    const unsigned short* Vc = Vf + bofs + ((size_t)ck << 13);
    // S^T = K x Q
    f32x4 st[4];
#pragma unroll
    for (int mf = 0; mf < 4; mf++) st[mf] = {0.f, 0.f, 0.f, 0.f};
#pragma unroll
    for (int cc = 0; cc < 4; cc++)
#pragma unroll
      for (int mf = 0; mf < 4; mf++) {
        bf16x8 kf = *(const bf16x8*)(Kc + ((cc * 4 + mf) << 9) + lane * 8);
        st[mf] = __builtin_amdgcn_mfma_f32_16x16x32_bf16(kf, qf[cc], st[mf], 0, 0, 0);
      }
    // hoist V loads: latency hides under the softmax chain
    bf16x8 vf[16];
#pragma unroll
    for (int nv = 0; nv < 16; nv++)
      vf[nv] = *(const bf16x8*)(Vc + (nv << 9) + lane * 8);
    // online softmax for q = ml
    float cmax = -1e30f;
#pragma unroll
    for (int mf = 0; mf < 4; mf++)
#pragma unroll
      for (int r = 0; r < 4; r++) cmax = fmaxf(cmax, st[mf][r]);
    cmax = fmaxf(cmax, __shfl_xor(cmax, 16));
    cmax = fmaxf(cmax, __shfl_xor(cmax, 32));
    float mnew = fmaxf(m_i, cmax);
    float alpha = __expf(m_i - mnew);
    float p[4][4];
    float psum = 0.f;
#pragma unroll
    for (int mf = 0; mf < 4; mf++)
#pragma unroll
      for (int r = 0; r < 4; r++) {
        float pv = __expf(st[mf][r] - mnew);
        p[mf][r] = pv; psum += pv;
      }
    psum += __shfl_xor(psum, 16);
    psum += __shfl_xor(psum, 32);
    l_i = l_i * alpha + psum;
    m_i = mnew;
    float a0 = __shfl(alpha, kg * 4 + 0), a1 = __shfl(alpha, kg * 4 + 1);
    float a2 = __shfl(alpha, kg * 4 + 2), a3 = __shfl(alpha, kg * 4 + 3);
#pragma unroll
    for (int nf = 0; nf < 8; nf++) {
      of[nf][0] *= a0; of[nf][1] *= a1; of[nf][2] *= a2; of[nf][3] *= a3;
    }
#pragma unroll
    for (int mf = 0; mf < 4; mf++) {
      unsigned int lo = (unsigned int)f2bf(p[mf][0]) | ((unsigned int)f2bf(p[mf][1]) << 16);
      unsigned int hi = (unsigned int)f2bf(p[mf][2]) | ((unsigned int)f2bf(p[mf][3]) << 16);
      *(uint2*)&Pl[wv][ml][mf * 16 + kg * 4] = make_uint2(lo, hi);
    }
    bf16x8 pa0 = *(const bf16x8*)&Pl[wv][ml][kg * 8];
    bf16x8 pa1 = *(const bf16x8*)&Pl[wv][ml][32 + kg * 8];
#pragma unroll
    for (int nf = 0; nf < 8; nf++) {
      of[nf] = __builtin_amdgcn_mfma_f32_16x16x32_bf16(pa0, vf[nf * 2 + 0], of[nf], 0, 0, 0);
      of[nf] = __builtin_amdgcn_mfma_f32_16x16x32_bf16(pa1, vf[nf * 2 + 1], of[nf], 0, 0, 0);
    }
  }

  // merge 4 K-splits
  if (kg == 0) { Ml[wv][ml] = m_i; Ll[wv][ml] = l_i; }
  __syncthreads();
  float m0 = Ml[0][ml], m1 = Ml[1][ml], m2 = Ml[2][ml], m3 = Ml[3][ml];
  float mt = fmaxf(fmaxf(m0, m1), fmaxf(m2, m3));
  float lt = Ll[0][ml] * __expf(m0 - mt) + Ll[1][ml] * __expf(m1 - mt) +
             Ll[2][ml] * __expf(m2 - mt) + Ll[3][ml] * __expf(m3 - mt);
  float s = __expf(m_i - mt) / lt;
  float s0 = __shfl(s, kg * 4 + 0), s1 = __shfl(s, kg * 4 + 1);
  float s2 = __shfl(s, kg * 4 + 2), s3 = __shfl(s, kg * 4 + 3);
#pragma unroll
  for (int nf = 0; nf < 8; nf++) {
    Ot[wv][kg * 4 + 0][nf * 16 + ml] = of[nf][0] * s0;
    Ot[wv][kg * 4 + 1][nf * 16 + ml] = of[nf][1] * s1;
    Ot[wv][kg * 4 + 2][nf * 16 + ml] = of[nf][2] * s2;
    Ot[wv][kg * 4 + 3][nf * 16 + ml] = of[nf][3] * s3;
  }
  __syncthreads();
  int base = tid * 8;
  int q = base >> 7, d = base & 127;
  float4 r0 = make_float4(0, 0, 0, 0), r1 = make_float4(0, 0, 0, 0);
#pragma unroll
  for (int w = 0; w < 4; w++) {
    float4 a = *(const float4*)&Ot[w][q][d];
    float4 c = *(const float4*)&Ot[w][q][d + 4];
    r0.x += a.x; r0.y += a.y; r0.z += a.z; r0.w += a.w;
    r1.x += c.x; r1.y += c.y; r1.z += c.z; r1.w += c.w;
  }
  float* Op = O + bofs + (size_t)(q0 + q) * 128 + d;
  *(float4*)Op = r0;
  *(float4*)(Op + 4) = r1;
}

// ---------- unpack packed attention output to bf16 (bt,h,w,C) ----------
__global__ __launch_bounds__(256) void unpack_att_bf16(
    const float* __restrict__ opk, unsigned short* __restrict__ att) {
  int idx = blockIdx.x * 256 + threadIdx.x;
  int oct = idx & 15, pix = idx >> 4;
  int w = pix & 63, h = (pix >> 6) & 63, bt = pix >> 12;
  int c0 = oct * 8;
  int g = c0 >> 5;
  int sh = g + 1, msk = (1 << sh) - 1;
  int ohn = 64 >> sh;
  int b = bt >> 2, t_i = bt & 3;
  int l = (t_i * ohn + (h >> sh)) * ohn + (w >> sh);
  int Dg = 32 << (2 * sh);
  int dbase = ((c0 & 31) << (2 * sh)) + ((h & msk) << sh) + (w & msk);
  const float* src = opk + ((size_t)g << 20) + ((size_t)b << 19) + (size_t)l * Dg;
  int dstep = 1 << (2 * sh);
  unsigned int pk[4];
#pragma unroll
  for (int j = 0; j < 4; j++) {
    unsigned short u0 = f2bf(src[dbase + (2 * j) * dstep]);
    unsigned short u1 = f2bf(src[dbase + (2 * j + 1) * dstep]);
    pk[j] = (unsigned int)u0 | ((unsigned int)u1 << 16);
  }
  *(uint4*)(att + ((size_t)pix * 128 + c0)) = make_uint4(pk[0], pk[1], pk[2], pk[3]);
}

// ---------- MFMA implicit-GEMM 3x3 conv: LDS row-staged, frag-major weights ----------
// Xs: 3 rows x 68 pix (halo 2, zero-padded) x 128ch, XOR-swizzled (slot^=pix&7).
template <int DIL, bool WF32, bool WBF16, bool RES>
__global__ __launch_bounds__(256) void conv_mfma(
    const unsigned short* __restrict__ Xb,
    const unsigned short* __restrict__ Wt,
    const float* __restrict__ Bi,
    const float* __restrict__ Rs,
    float* __restrict__ Yf,
    unsigned short* __restrict__ Ybf) {
  __shared__ __align__(16) char Xs[3 * 17408];
  int tid = threadIdx.x;
  int lane = tid & 63, wid = tid >> 6;
  int wm = wid & 1, wn = wid >> 1;
  int ml = lane & 15, kg = lane >> 4;
  int bt = blockIdx.x >> 6, h = blockIdx.x & 63;
  const int wbase = wn * 32;

  // stage 3 input rows (zero rows/pixels outside the image)
  for (int idx = tid; idx < 3264; idx += 256) {
    int row = idx / 1088, rem = idx - row * 1088;
    int pix = rem >> 4, cs = rem & 15;
    int r = h + (row - 1) * DIL;
    int w = pix - 2;
    bf16x8 v = {0, 0, 0, 0, 0, 0, 0, 0};
    if ((unsigned)r < 64u && (unsigned)w < 64u)
      v = *(const bf16x8*)(Xb + (((size_t)(bt * 64 + r) * 64 + w) << 7) + cs * 8);
    int sw = (cs & 8) | ((cs ^ (pix & 7)) & 7);
    *(bf16x8*)(&Xs[row * 17408 + pix * 256 + sw * 16]) = v;
  }
  __syncthreads();

  f32x4 acc[4][2];
#pragma unroll
  for (int i = 0; i < 4; i++)
#pragma unroll
    for (int j = 0; j < 2; j++)
      acc[i][j] = {0.f, 0.f, 0.f, 0.f};

#pragma unroll
  for (int kh = 0; kh < 3; kh++) {
#pragma unroll
    for (int kw = 0; kw < 3; kw++) {
      int shf = (kw - 1) * DIL + 2;
#pragma unroll
      for (int cs4 = 0; cs4 < 4; cs4++) {
        // A: contiguous 1KB frag-major weight loads
        const unsigned short* Ap =
            Wt + ((size_t)(((kh * 3 + kw) * 4 + cs4) * 2 + wm) << 11) + lane * 8;
        bf16x8 a[4], bfr[2];
#pragma unroll
        for (int mf = 0; mf < 4; mf++)
          a[mf] = *(const bf16x8*)(Ap + (mf << 9));
        // B: swizzled LDS reads
#pragma unroll
        for (int nf = 0; nf < 2; nf++) {
          int px = wbase + nf * 16 + ml + shf;  // [0, 67]
          int cslot = cs4 * 4 + kg;
          int sw = (cslot & 8) | ((cslot ^ (px & 7)) & 7);
          bfr[nf] = *(const bf16x8*)(&Xs[kh * 17408 + px * 256 + sw * 16]);
        }
#pragma unroll
        for (int mf = 0; mf < 4; mf++)
#pragma unroll
          for (int nf = 0; nf < 2; nf++)
            acc[mf][nf] = __builtin_amdgcn_mfma_f32_16x16x32_bf16(
                a[mf], bfr[nf], acc[mf][nf], 0, 0, 0);
      }
    }
  }

#pragma unroll
  for (int mf = 0; mf < 4; mf++) {
    int obase = wm * 64 + mf * 16 + kg * 4;
#pragma unroll
    for (int nf = 0; nf < 2; nf++) {
      int w = wbase + nf * 16 + ml;
      float v[4];
#pragma unroll
      for (int r4 = 0; r4 < 4; r4++) {
        int o = obase + r4;
        float val = acc[mf][nf][r4] + Bi[o];
        val = val > 0.f ? val : 0.2f * val;
        size_t idx = (((size_t)bt * 128 + o) * 64 + h) * 64 + w;
        if (RES) val += Rs[idx];
        if (WF32) Yf[idx] = val;
        v[r4] = val;
      }
      if (WBF16) {
        unsigned int lo = (unsigned int)f2bf(v[0]) | ((unsigned int)f2bf(v[1]) << 16);
        unsigned int hi = (unsigned int)f2bf(v[2]) | ((unsigned int)f2bf(v[3]) << 16);
        *(uint2*)(Ybf + (((size_t)bt * 4096 + h * 64 + w) * 128 + obase)) =
            make_uint2(lo, hi);
      }
    }
  }
}

extern "C" void kernel_launch(void* const* d_in, const int* in_sizes, int n_in,
                              void* d_out, int out_size, void* d_ws, size_t ws_size,
                              hipStream_t stream) {
  (void)in_sizes; (void)n_in; (void)out_size; (void)ws_size;
  const float* x   = (const float*)d_in[0];
  const float* Wq  = (const float*)d_in[1];
  const float* bq  = (const float*)d_in[2];
  const float* Wk  = (const float*)d_in[3];
  const float* bk  = (const float*)d_in[4];
  const float* Wv  = (const float*)d_in[5];
  const float* bv  = (const float*)d_in[6];
  const float* Wo  = (const float*)d_in[7];
  const float* bo  = (const float*)d_in[8];
  const float* Wf1 = (const float*)d_in[9];
  const float* bf1 = (const float*)d_in[10];
  const float* Wf2 = (const float*)d_in[11];
  const float* bf2 = (const float*)d_in[12];
  float* out = (float*)d_out;

  // workspace layout (~91.2 MB)
  char* wsb = (char*)d_ws;
  float* xcur = (float*)(wsb);                                  // 16 MB
  float* opk  = (float*)(wsb + 16777216);                       // 16 MB
  float* S    = (float*)(wsb + 33554432);                       //  8 MB
  unsigned short* Qp = (unsigned short*)(wsb + 41943040);       //  8 MB (g1-3)
  unsigned short* Kp = (unsigned short*)(wsb + 50331648);       //  8 MB (g1-3)
  unsigned short* Vt = (unsigned short*)(wsb + 58720256);       //  8 MB (g1-3)
  unsigned short* Qf = (unsigned short*)(wsb + 67108864);       //  2 MB (g0)
  unsigned short* Kf = (unsigned short*)(wsb + 69206016);       //  2 MB (g0)
  unsigned short* Vf = (unsigned short*)(wsb + 71303168);       //  2 MB (g0)
  unsigned short* att_hwc  = (unsigned short*)(wsb + 73400320); //  8 MB (=f1_hwc)
  unsigned short* xcur_hwc = (unsigned short*)(wsb + 81788928); //  8 MB (=Pb)
  unsigned short* Wt0 = (unsigned short*)(wsb + 90177536);
  unsigned short* Wt1 = (unsigned short*)(wsb + 90472448);
  unsigned short* Wt2 = (unsigned short*)(wsb + 90767360);
  unsigned short* Wqb = (unsigned short*)(wsb + 91062272);
  unsigned short* Wkb = (unsigned short*)(wsb + 91095040);
  unsigned short* Wvb = (unsigned short*)(wsb + 91127808);
  unsigned short* f1_hwc = att_hwc;
  unsigned short* Pb = xcur_hwc;

  hipMemcpyAsync(xcur, x, 16777216, hipMemcpyDeviceToDevice, stream);

  const int Ls[3] = {1024, 256, 64};
  const int Ds[3] = {512, 2048, 8192};
  dim3 blk(256);

  x2hwc<<<dim3(128, 16), blk, 0, stream>>>(x, xcur_hwc);

  for (int layer = 0; layer < 2; layer++) {
    const float* wq  = Wq  + layer * 16384;
    const float* wk  = Wk  + layer * 16384;
    const float* wv  = Wv  + layer * 16384;
    const float* bq_ = bq  + layer * 128;
    const float* bk_ = bk  + layer * 128;
    const float* bv_ = bv  + layer * 128;
    const float* wo  = Wo  + layer * 147456;
    const float* bo_ = bo  + layer * 128;
    const float* wf1 = Wf1 + layer * 147456;
    const float* bf1_ = bf1 + layer * 128;
    const float* wf2 = Wf2 + layer * 147456;
    const float* bf2_ = bf2 + layer * 128;

    wprep3<<<dim3(576, 3), blk, 0, stream>>>(wo, wf1, wf2, Wt0, Wt1, Wt2);
    wprep1<<<dim3(64, 3), blk, 0, stream>>>(wq, wk, wv, Wqb, Wkb, Wvb);

    qkv_pack<0><<<dim3(512, 2), blk, 0, stream>>>(xcur_hwc, Wqb, bq_, Qp, nullptr, Qf);
    qkv_pack<1><<<dim3(512, 2), blk, 0, stream>>>(xcur_hwc, Wkb, bk_, Kp, nullptr, Kf);
    qkv_pack<2><<<dim3(512, 2), blk, 0, stream>>>(xcur_hwc, Wvb, bv_, nullptr, Vt, Vf);

    flash_mfma<<<dim3(512), blk, 0, stream>>>(Qf, Kf, Vf, opk);

    for (int gg = 0; gg < 3; gg++) {
      int g = gg + 1;
      size_t go = (size_t)g << 20;
      int L = Ls[gg], D = Ds[gg];
      gemm_tn<<<dim3(L / 64, L / 64, 2), blk, 0, stream>>>(
          Qp + go, Kp + go, S, D, D, D, L, 1LL << 19, 1LL << 19, (long long)L * L);
      softmax_bf16<<<dim3(2 * L), blk, 0, stream>>>(S, Pb, L);
      gemm_tn<<<dim3(D / 64, L / 64, 2), blk, 0, stream>>>(
          Pb, Vt + go, opk + go, L, L, L, D, (long long)L * L, 1LL << 19, 1LL << 19);
    }

    unpack_att_bf16<<<dim3(2048), blk, 0, stream>>>(opk, att_hwc);

    conv_mfma<1, true, true, true><<<dim3(512), blk, 0, stream>>>(
        att_hwc, Wt0, bo_, xcur, xcur, xcur_hwc);
    conv_mfma<2, false, true, false><<<dim3(512), blk, 0, stream>>>(
        xcur_hwc, Wt1, bf1_, nullptr, nullptr, f1_hwc);
    if (layer == 0) {
      conv_mfma<1, true, true, true><<<dim3(512), blk, 0, stream>>>(
          f1_hwc, Wt2, bf2_, xcur, xcur, xcur_hwc);
    } else {
      conv_mfma<1, true, false, true><<<dim3(512), blk, 0, stream>>>(
          f1_hwc, Wt2, bf2_, xcur, out, nullptr);
    }
  }
}

// Round 7
// 630.861 us; speedup vs baseline: 13.2938x; 1.3597x over previous
//
#include <hip/hip_runtime.h>

// ---------- bf16 helpers (manual, RNE) ----------
__device__ __forceinline__ unsigned short f2bf(float f) {
  union { float f; unsigned int i; } c; c.f = f;
  unsigned int i = c.i;
  i += 0x7fffu + ((i >> 16) & 1u);
  return (unsigned short)(i >> 16);
}

typedef __attribute__((ext_vector_type(8))) short bf16x8;
typedef __attribute__((ext_vector_type(4))) float f32x4;

// Geometry: x is (bt=8, C=128, 64, 64); bt = b*4 + t (b=2, t=4).
// Head group g (0..3): patch p = 1<<(g+1), dk = 32 channels.
// Packed token layout per group: (b, l, d); L*D = 1<<19; group base = g<<20.
// MFMA convention (verified):
//   A-frag: lane(ml=lane&15,kg=lane>>4) holds A[row=ml][c=kg*8+j]
//   B-frag: lane holds B[c=kg*8+j][col=ml]
//   C/D   : lane holds D[row=kg*4+reg][col=ml]
// g0 fragment-major layouts (contiguous 1KB per wave frag-load):
//   Qf[b][qt][cc4][lane64][8]   element (q=qt*16+ml, d=cc*32+kg*8+j)
//   Kf[b][ck64][cc4][mf4][lane64][8]  (key=ck*64+mf*16+ml, d=cc*32+kg*8+j)
//   Vf[b][ck64][nf8][part2][lane64][8] (key=ck*64+part*32+kg*8+j, d=nf*16+ml)

// ---------- x (NCHW f32) -> x_hwc (pix_g, 128) bf16 ----------
__global__ __launch_bounds__(256) void x2hwc(const float* __restrict__ X,
                                             unsigned short* __restrict__ Xh) {
  int pixg = blockIdx.x * 256 + threadIdx.x;  // 32768
  int c0 = blockIdx.y * 8;
  int bt = pixg >> 12, pix = pixg & 4095;
  const float* src = X + ((size_t)bt << 19) + (size_t)c0 * 4096 + pix;
  unsigned int pk[4];
#pragma unroll
  for (int j = 0; j < 4; j++) {
    unsigned short u0 = f2bf(src[(2 * j) * 4096]);
    unsigned short u1 = f2bf(src[(2 * j + 1) * 4096]);
    pk[j] = (unsigned int)u0 | ((unsigned int)u1 << 16);
  }
  *(uint4*)(Xh + (size_t)pixg * 128 + c0) = make_uint4(pk[0], pk[1], pk[2], pk[3]);
}

// ---------- weight prep 3x3: (o,i,3,3) f32 -> fragment-major bf16 ----------
// out idx: [tap9][cs4][wm2][mf4][lane64][j8]; o=wm*64+mf*16+ml, i=cs*32+kg*8+j
__global__ __launch_bounds__(256) void wprep3(
    const float* __restrict__ s0, const float* __restrict__ s1,
    const float* __restrict__ s2, unsigned short* __restrict__ d0,
    unsigned short* __restrict__ d1, unsigned short* __restrict__ d2) {
  int idx = blockIdx.x * 256 + threadIdx.x;  // 147456
  const float* s = blockIdx.y == 0 ? s0 : (blockIdx.y == 1 ? s1 : s2);
  unsigned short* d = blockIdx.y == 0 ? d0 : (blockIdx.y == 1 ? d1 : d2);
  int j = idx & 7;
  int lane = (idx >> 3) & 63;
  int kg = lane >> 4, ml = lane & 15;
  int f = idx >> 9;
  int mf = f & 3, wm = (f >> 2) & 1, cs = (f >> 3) & 3, tap = f >> 5;
  int o = wm * 64 + mf * 16 + ml;
  int i = cs * 32 + kg * 8 + j;
  d[idx] = f2bf(s[(size_t)(o * 128 + i) * 9 + tap]);
}

// ---------- weight prep 1x1 ----------
__global__ __launch_bounds__(256) void wprep1(
    const float* __restrict__ s0, const float* __restrict__ s1,
    const float* __restrict__ s2, unsigned short* __restrict__ d0,
    unsigned short* __restrict__ d1, unsigned short* __restrict__ d2) {
  int idx = blockIdx.x * 256 + threadIdx.x;  // 16384
  const float* s = blockIdx.y == 0 ? s0 : (blockIdx.y == 1 ? s1 : s2);
  unsigned short* d = blockIdx.y == 0 ? d0 : (blockIdx.y == 1 ? d1 : d2);
  d[idx] = f2bf(s[idx]);
}

// ---------- QKV projection MFMA GEMM with pack epilogue ----------
// MODE 0=q, 1=k, 2=v. g0 -> fragment-major Ff; g1-3 -> packed P (q,k) / Vt (v).
template <int MODE>
__global__ __launch_bounds__(256) void qkv_pack(
    const unsigned short* __restrict__ Xh, const unsigned short* __restrict__ Wb,
    const float* __restrict__ Bi, unsigned short* __restrict__ P,
    unsigned short* __restrict__ VtP, unsigned short* __restrict__ Ff) {
  int tid = threadIdx.x, lane = tid & 63, wid = tid >> 6;
  int wm = wid & 1, wn = wid >> 1;
  int ml = lane & 15, kg = lane >> 4;
  int m_base = blockIdx.y * 64 + wm * 32;
  int n_base = blockIdx.x * 64 + wn * 32;
  f32x4 acc[2][2];
#pragma unroll
  for (int i = 0; i < 2; i++)
#pragma unroll
    for (int j = 0; j < 2; j++) acc[i][j] = {0.f, 0.f, 0.f, 0.f};
#pragma unroll
  for (int kc = 0; kc < 128; kc += 32) {
    bf16x8 af[2], bfr[2];
#pragma unroll
    for (int mf = 0; mf < 2; mf++)
      af[mf] = *(const bf16x8*)(Wb + (size_t)(m_base + mf * 16 + ml) * 128 + kc + kg * 8);
#pragma unroll
    for (int nf = 0; nf < 2; nf++)
      bfr[nf] = *(const bf16x8*)(Xh + (size_t)(n_base + nf * 16 + ml) * 128 + kc + kg * 8);
#pragma unroll
    for (int mf = 0; mf < 2; mf++)
#pragma unroll
      for (int nf = 0; nf < 2; nf++)
        acc[mf][nf] = __builtin_amdgcn_mfma_f32_16x16x32_bf16(af[mf], bfr[nf], acc[mf][nf], 0, 0, 0);
  }
#pragma unroll
  for (int mf = 0; mf < 2; mf++)
#pragma unroll
    for (int nf = 0; nf < 2; nf++)
#pragma unroll
      for (int r = 0; r < 4; r++) {
        int c = m_base + mf * 16 + kg * 4 + r;
        int pixg = n_base + nf * 16 + ml;
        float val = acc[mf][nf][r] + Bi[c];
        int bt = pixg >> 12, pix = pixg & 4095;
        int h = pix >> 6, w = pix & 63;
        int g = c >> 5, sh = g + 1, msk = (1 << sh) - 1, ohn = 64 >> sh;
        int b = bt >> 2, t_i = bt & 3;
        int l = (t_i * ohn + (h >> sh)) * ohn + (w >> sh);
        int Dg = 32 << (2 * sh);
        int d = ((c & 31) << (2 * sh)) + ((h & msk) << sh) + (w & msk);
        if (MODE == 0) val *= rsqrtf((float)Dg);
        unsigned short bv = f2bf(val);
        size_t bofs = (size_t)b << 19;
        if (g == 0) {
          if (MODE == 0) {
            int qt = l >> 4, mlq = l & 15, cc = d >> 5, kgq = (d >> 3) & 3, j = d & 7;
            Ff[bofs + ((size_t)(qt * 4 + cc) << 9) + (kgq * 16 + mlq) * 8 + j] = bv;
          } else if (MODE == 1) {
            int ck = l >> 6, mfk = (l >> 4) & 3, mlk = l & 15;
            int cc = d >> 5, kgk = (d >> 3) & 3, j = d & 7;
            Ff[bofs + ((size_t)(ck * 16 + cc * 4 + mfk) << 9) + (kgk * 16 + mlk) * 8 + j] = bv;
          } else {
            int ck = l >> 6, part = (l >> 5) & 1, kgv = (l >> 3) & 3, j = l & 7;
            int nf = d >> 4, mlv = d & 15;
            Ff[bofs + ((size_t)(ck * 16 + nf * 2 + part) << 9) + (kgv * 16 + mlv) * 8 + j] = bv;
          }
        } else {
          size_t base = ((size_t)g << 20) + bofs;
          if (MODE != 2) {
            P[base + (size_t)l * Dg + d] = bv;
          } else {
            int Lg = 16384 >> (2 * sh);
            VtP[base + (size_t)d * Lg + l] = bv;
          }
        }
      }
}

// ---------- generic MFMA GEMM: C(MxN) f32 = A(MxK) * B(NxK)^T, bf16 ----------
__global__ __launch_bounds__(256) void gemm_tn(
    const unsigned short* __restrict__ A, const unsigned short* __restrict__ B,
    float* __restrict__ C, int K, int lda, int ldb, int ldc,
    long long sA, long long sB, long long sC) {
  int tid = threadIdx.x, lane = tid & 63, wid = tid >> 6;
  int wm = wid & 1, wn = wid >> 1;
  int ml = lane & 15, kg = lane >> 4;
  A += (size_t)blockIdx.z * sA;
  B += (size_t)blockIdx.z * sB;
  C += (size_t)blockIdx.z * sC;
  int m_base = blockIdx.y * 64 + wm * 32;
  int n_base = blockIdx.x * 64 + wn * 32;
  f32x4 acc[2][2];
#pragma unroll
  for (int i = 0; i < 2; i++)
#pragma unroll
    for (int j = 0; j < 2; j++) acc[i][j] = {0.f, 0.f, 0.f, 0.f};
  for (int kc = 0; kc < K; kc += 32) {
    bf16x8 af[2], bfr[2];
#pragma unroll
    for (int mf = 0; mf < 2; mf++)
      af[mf] = *(const bf16x8*)(A + (size_t)(m_base + mf * 16 + ml) * lda + kc + kg * 8);
#pragma unroll
    for (int nf = 0; nf < 2; nf++)
      bfr[nf] = *(const bf16x8*)(B + (size_t)(n_base + nf * 16 + ml) * ldb + kc + kg * 8);
#pragma unroll
    for (int mf = 0; mf < 2; mf++)
#pragma unroll
      for (int nf = 0; nf < 2; nf++)
        acc[mf][nf] = __builtin_amdgcn_mfma_f32_16x16x32_bf16(af[mf], bfr[nf], acc[mf][nf], 0, 0, 0);
  }
#pragma unroll
  for (int mf = 0; mf < 2; mf++)
#pragma unroll
    for (int nf = 0; nf < 2; nf++)
#pragma unroll
      for (int r = 0; r < 4; r++) {
        int m = m_base + mf * 16 + kg * 4 + r;
        int n = n_base + nf * 16 + ml;
        C[(size_t)m * ldc + n] = acc[mf][nf][r];
      }
}

// ---------- split-K MFMA GEMM: partial tiles, KC=128 per split ----------
// grid (L/64, L/64, 2*nsplit); bz: b=bz&1, split=bz>>1.
// Writes Cp[(split*2+b)*L*L + m*L + n] (own tile per split -> no atomics).
__global__ __launch_bounds__(256) void gemm_tn_sk(
    const unsigned short* __restrict__ A, const unsigned short* __restrict__ B,
    float* __restrict__ Cp, int lda, int ldb, int L,
    long long sA, long long sB) {
  constexpr int KC = 128;
  int tid = threadIdx.x, lane = tid & 63, wid = tid >> 6;
  int wm = wid & 1, wn = wid >> 1;
  int ml = lane & 15, kg = lane >> 4;
  int bz = blockIdx.z, b = bz & 1, split = bz >> 1;
  A += (size_t)b * sA + split * KC;
  B += (size_t)b * sB + split * KC;
  float* Ct = Cp + (size_t)bz * L * L;
  int m_base = blockIdx.y * 64 + wm * 32;
  int n_base = blockIdx.x * 64 + wn * 32;
  f32x4 acc[2][2];
#pragma unroll
  for (int i = 0; i < 2; i++)
#pragma unroll
    for (int j = 0; j < 2; j++) acc[i][j] = {0.f, 0.f, 0.f, 0.f};
#pragma unroll
  for (int kc = 0; kc < KC; kc += 32) {
    bf16x8 af[2], bfr[2];
#pragma unroll
    for (int mf = 0; mf < 2; mf++)
      af[mf] = *(const bf16x8*)(A + (size_t)(m_base + mf * 16 + ml) * lda + kc + kg * 8);
#pragma unroll
    for (int nf = 0; nf < 2; nf++)
      bfr[nf] = *(const bf16x8*)(B + (size_t)(n_base + nf * 16 + ml) * ldb + kc + kg * 8);
#pragma unroll
    for (int mf = 0; mf < 2; mf++)
#pragma unroll
      for (int nf = 0; nf < 2; nf++)
        acc[mf][nf] = __builtin_amdgcn_mfma_f32_16x16x32_bf16(af[mf], bfr[nf], acc[mf][nf], 0, 0, 0);
  }
#pragma unroll
  for (int mf = 0; mf < 2; mf++)
#pragma unroll
    for (int nf = 0; nf < 2; nf++)
#pragma unroll
      for (int r = 0; r < 4; r++) {
        int m = m_base + mf * 16 + kg * 4 + r;
        int n = n_base + nf * 16 + ml;
        Ct[(size_t)m * L + n] = acc[mf][nf][r];
      }
}

// ---------- sum partials + row softmax -> bf16 (L <= 256) ----------
__global__ __launch_bounds__(256) void softmax_sum_bf16(
    const float* __restrict__ Sp, unsigned short* __restrict__ P, int L, int nsplit) {
  __shared__ float red[256];
  int tid = threadIdx.x;
  int b = blockIdx.x / L, m = blockIdx.x - b * L;
  const float* row = Sp + ((size_t)b * L + m) * L;
  long long pstride = 2LL * L * L;
  float val = 0.f;
  if (tid < L) {
    for (int s = 0; s < nsplit; s++) val += row[(size_t)s * pstride + tid];
  }
  red[tid] = (tid < L) ? val : -1e30f;
  __syncthreads();
  for (int s = 128; s > 0; s >>= 1) {
    if (tid < s) red[tid] = fmaxf(red[tid], red[tid + s]);
    __syncthreads();
  }
  float mx = red[0]; __syncthreads();
  float e = (tid < L) ? __expf(val - mx) : 0.f;
  red[tid] = e; __syncthreads();
  for (int s = 128; s > 0; s >>= 1) {
    if (tid < s) red[tid] += red[tid + s];
    __syncthreads();
  }
  float inv = 1.f / red[0];
  if (tid < L) P[((size_t)b * L + m) * L + tid] = f2bf(e * inv);
}

// ---------- row softmax f32 -> bf16 (large L) ----------
__global__ __launch_bounds__(256) void softmax_bf16(float* __restrict__ S,
                                                    unsigned short* __restrict__ P, int L) {
  __shared__ float red[256];
  int tid = threadIdx.x;
  float* p = S + (size_t)blockIdx.x * L;
  unsigned short* o = P + (size_t)blockIdx.x * L;
  float mx = -1e30f;
  for (int e = tid; e < L; e += 256) mx = fmaxf(mx, p[e]);
  red[tid] = mx; __syncthreads();
  for (int s = 128; s > 0; s >>= 1) {
    if (tid < s) red[tid] = fmaxf(red[tid], red[tid + s]);
    __syncthreads();
  }
  mx = red[0]; __syncthreads();
  float sm = 0.f;
  for (int e = tid; e < L; e += 256) {
    float v = __expf(p[e] - mx);
    p[e] = v; sm += v;
  }
  red[tid] = sm; __syncthreads();
  for (int s = 128; s > 0; s >>= 1) {
    if (tid < s) red[tid] += red[tid + s];
    __syncthreads();
  }
  float inv = 1.f / red[0];
  for (int e = tid; e < L; e += 256) o[e] = f2bf(p[e] * inv);
}

// ---------- MFMA flash attention group 0 (L=4096, D=128), frag-major inputs ----------
__global__ __launch_bounds__(256, 2) void flash_mfma(
    const unsigned short* __restrict__ Qf, const unsigned short* __restrict__ Kf,
    const unsigned short* __restrict__ Vf, float* __restrict__ O) {
  __shared__ float Ot[4][16][128];
  __shared__ unsigned short Pl[4][16][72];
  __shared__ float Ml[4][16], Ll[4][16];
  int tid = threadIdx.x, lane = tid & 63, wv = tid >> 6;
  int ml = lane & 15, kg = lane >> 4;
  int b = blockIdx.x >> 8, qt = blockIdx.x & 255;
  size_t bofs = (size_t)b << 19;
  int q0 = qt * 16;

  bf16x8 qf[4];
#pragma unroll
  for (int cc = 0; cc < 4; cc++)
    qf[cc] = *(const bf16x8*)(Qf + bofs + ((size_t)(qt * 4 + cc) << 9) + lane * 8);

  float m_i = -1e30f, l_i = 0.f;
  f32x4 of[8];
#pragma unroll
  for (int nf = 0; nf < 8; nf++) of[nf] = {0.f, 0.f, 0.f, 0.f};

  for (int ck = wv * 16; ck < wv * 16 + 16; ck++) {
    const unsigned short* Kc = Kf + bofs + ((size_t)ck << 13);
    const unsigned short* Vc = Vf + bofs + ((size_t)ck << 13);
    // S^T = K x Q
    f32x4 st[4];
#pragma unroll
    for (int mf = 0; mf < 4; mf++) st[mf] = {0.f, 0.f, 0.f, 0.f};
#pragma unroll
    for (int cc = 0; cc < 4; cc++)
#pragma unroll
      for (int mf = 0; mf < 4; mf++) {
        bf16x8 kf = *(const bf16x8*)(Kc + ((cc * 4 + mf) << 9) + lane * 8);
        st[mf] = __builtin_amdgcn_mfma_f32_16x16x32_bf16(kf, qf[cc], st[mf], 0, 0, 0);
      }
    // hoist V loads: latency hides under the softmax chain
    bf16x8 vf[16];
#pragma unroll
    for (int nv = 0; nv < 16; nv++)
      vf[nv] = *(const bf16x8*)(Vc + (nv << 9) + lane * 8);
    // online softmax for q = ml
    float cmax = -1e30f;
#pragma unroll
    for (int mf = 0; mf < 4; mf++)
#pragma unroll
      for (int r = 0; r < 4; r++) cmax = fmaxf(cmax, st[mf][r]);
    cmax = fmaxf(cmax, __shfl_xor(cmax, 16));
    cmax = fmaxf(cmax, __shfl_xor(cmax, 32));
    float mnew = fmaxf(m_i, cmax);
    float alpha = __expf(m_i - mnew);
    float p[4][4];
    float psum = 0.f;
#pragma unroll
    for (int mf = 0; mf < 4; mf++)
#pragma unroll
      for (int r = 0; r < 4; r++) {
        float pv = __expf(st[mf][r] - mnew);
        p[mf][r] = pv; psum += pv;
      }
    psum += __shfl_xor(psum, 16);
    psum += __shfl_xor(psum, 32);
    l_i = l_i * alpha + psum;
    m_i = mnew;
    float a0 = __shfl(alpha, kg * 4 + 0), a1 = __shfl(alpha, kg * 4 + 1);
    float a2 = __shfl(alpha, kg * 4 + 2), a3 = __shfl(alpha, kg * 4 + 3);
#pragma unroll
    for (int nf = 0; nf < 8; nf++) {
      of[nf][0] *= a0; of[nf][1] *= a1; of[nf][2] *= a2; of[nf][3] *= a3;
    }
#pragma unroll
    for (int mf = 0; mf < 4; mf++) {
      unsigned int lo = (unsigned int)f2bf(p[mf][0]) | ((unsigned int)f2bf(p[mf][1]) << 16);
      unsigned int hi = (unsigned int)f2bf(p[mf][2]) | ((unsigned int)f2bf(p[mf][3]) << 16);
      *(uint2*)&Pl[wv][ml][mf * 16 + kg * 4] = make_uint2(lo, hi);
    }
    bf16x8 pa0 = *(const bf16x8*)&Pl[wv][ml][kg * 8];
    bf16x8 pa1 = *(const bf16x8*)&Pl[wv][ml][32 + kg * 8];
#pragma unroll
    for (int nf = 0; nf < 8; nf++) {
      of[nf] = __builtin_amdgcn_mfma_f32_16x16x32_bf16(pa0, vf[nf * 2 + 0], of[nf], 0, 0, 0);
      of[nf] = __builtin_amdgcn_mfma_f32_16x16x32_bf16(pa1, vf[nf * 2 + 1], of[nf], 0, 0, 0);
    }
  }

  // merge 4 K-splits
  if (kg == 0) { Ml[wv][ml] = m_i; Ll[wv][ml] = l_i; }
  __syncthreads();
  float m0 = Ml[0][ml], m1 = Ml[1][ml], m2 = Ml[2][ml], m3 = Ml[3][ml];
  float mt = fmaxf(fmaxf(m0, m1), fmaxf(m2, m3));
  float lt = Ll[0][ml] * __expf(m0 - mt) + Ll[1][ml] * __expf(m1 - mt) +
             Ll[2][ml] * __expf(m2 - mt) + Ll[3][ml] * __expf(m3 - mt);
  float s = __expf(m_i - mt) / lt;
  float s0 = __shfl(s, kg * 4 + 0), s1 = __shfl(s, kg * 4 + 1);
  float s2 = __shfl(s, kg * 4 + 2), s3 = __shfl(s, kg * 4 + 3);
#pragma unroll
  for (int nf = 0; nf < 8; nf++) {
    Ot[wv][kg * 4 + 0][nf * 16 + ml] = of[nf][0] * s0;
    Ot[wv][kg * 4 + 1][nf * 16 + ml] = of[nf][1] * s1;
    Ot[wv][kg * 4 + 2][nf * 16 + ml] = of[nf][2] * s2;
    Ot[wv][kg * 4 + 3][nf * 16 + ml] = of[nf][3] * s3;
  }
  __syncthreads();
  int base = tid * 8;
  int q = base >> 7, d = base & 127;
  float4 r0 = make_float4(0, 0, 0, 0), r1 = make_float4(0, 0, 0, 0);
#pragma unroll
  for (int w = 0; w < 4; w++) {
    float4 a = *(const float4*)&Ot[w][q][d];
    float4 c = *(const float4*)&Ot[w][q][d + 4];
    r0.x += a.x; r0.y += a.y; r0.z += a.z; r0.w += a.w;
    r1.x += c.x; r1.y += c.y; r1.z += c.z; r1.w += c.w;
  }
  float* Op = O + bofs + (size_t)(q0 + q) * 128 + d;
  *(float4*)Op = r0;
  *(float4*)(Op + 4) = r1;
}

// ---------- unpack packed attention output to bf16 (bt,h,w,C) ----------
__global__ __launch_bounds__(256) void unpack_att_bf16(
    const float* __restrict__ opk, unsigned short* __restrict__ att) {
  int idx = blockIdx.x * 256 + threadIdx.x;
  int oct = idx & 15, pix = idx >> 4;
  int w = pix & 63, h = (pix >> 6) & 63, bt = pix >> 12;
  int c0 = oct * 8;
  int g = c0 >> 5;
  int sh = g + 1, msk = (1 << sh) - 1;
  int ohn = 64 >> sh;
  int b = bt >> 2, t_i = bt & 3;
  int l = (t_i * ohn + (h >> sh)) * ohn + (w >> sh);
  int Dg = 32 << (2 * sh);
  int dbase = ((c0 & 31) << (2 * sh)) + ((h & msk) << sh) + (w & msk);
  const float* src = opk + ((size_t)g << 20) + ((size_t)b << 19) + (size_t)l * Dg;
  int dstep = 1 << (2 * sh);
  unsigned int pk[4];
#pragma unroll
  for (int j = 0; j < 4; j++) {
    unsigned short u0 = f2bf(src[dbase + (2 * j) * dstep]);
    unsigned short u1 = f2bf(src[dbase + (2 * j + 1) * dstep]);
    pk[j] = (unsigned int)u0 | ((unsigned int)u1 << 16);
  }
  *(uint4*)(att + ((size_t)pix * 128 + c0)) = make_uint4(pk[0], pk[1], pk[2], pk[3]);
}

// ---------- MFMA implicit-GEMM 3x3 conv: LDS row-staged, frag-major weights ----------
// Xs: 3 rows x 68 pix (halo 2, zero-padded) x 128ch, XOR-swizzled (slot^=pix&7).
template <int DIL, bool WF32, bool WBF16, bool RES>
__global__ __launch_bounds__(256) void conv_mfma(
    const unsigned short* __restrict__ Xb,
    const unsigned short* __restrict__ Wt,
    const float* __restrict__ Bi,
    const float* __restrict__ Rs,
    float* __restrict__ Yf,
    unsigned short* __restrict__ Ybf) {
  __shared__ __align__(16) char Xs[3 * 17408];
  int tid = threadIdx.x;
  int lane = tid & 63, wid = tid >> 6;
  int wm = wid & 1, wn = wid >> 1;
  int ml = lane & 15, kg = lane >> 4;
  int bt = blockIdx.x >> 6, h = blockIdx.x & 63;
  const int wbase = wn * 32;

  // stage 3 input rows (zero rows/pixels outside the image)
  for (int idx = tid; idx < 3264; idx += 256) {
    int row = idx / 1088, rem = idx - row * 1088;
    int pix = rem >> 4, cs = rem & 15;
    int r = h + (row - 1) * DIL;
    int w = pix - 2;
    bf16x8 v = {0, 0, 0, 0, 0, 0, 0, 0};
    if ((unsigned)r < 64u && (unsigned)w < 64u)
      v = *(const bf16x8*)(Xb + (((size_t)(bt * 64 + r) * 64 + w) << 7) + cs * 8);
    int sw = (cs & 8) | ((cs ^ (pix & 7)) & 7);
    *(bf16x8*)(&Xs[row * 17408 + pix * 256 + sw * 16]) = v;
  }
  __syncthreads();

  f32x4 acc[4][2];
#pragma unroll
  for (int i = 0; i < 4; i++)
#pragma unroll
    for (int j = 0; j < 2; j++)
      acc[i][j] = {0.f, 0.f, 0.f, 0.f};

#pragma unroll
  for (int kh = 0; kh < 3; kh++) {
#pragma unroll
    for (int kw = 0; kw < 3; kw++) {
      int shf = (kw - 1) * DIL + 2;
#pragma unroll
      for (int cs4 = 0; cs4 < 4; cs4++) {
        // A: contiguous 1KB frag-major weight loads
        const unsigned short* Ap =
            Wt + ((size_t)(((kh * 3 + kw) * 4 + cs4) * 2 + wm) << 11) + lane * 8;
        bf16x8 a[4], bfr[2];
#pragma unroll
        for (int mf = 0; mf < 4; mf++)
          a[mf] = *(const bf16x8*)(Ap + (mf << 9));
        // B: swizzled LDS reads
#pragma unroll
        for (int nf = 0; nf < 2; nf++) {
          int px = wbase + nf * 16 + ml + shf;  // [0, 67]
          int cslot = cs4 * 4 + kg;
          int sw = (cslot & 8) | ((cslot ^ (px & 7)) & 7);
          bfr[nf] = *(const bf16x8*)(&Xs[kh * 17408 + px * 256 + sw * 16]);
        }
#pragma unroll
        for (int mf = 0; mf < 4; mf++)
#pragma unroll
          for (int nf = 0; nf < 2; nf++)
            acc[mf][nf] = __builtin_amdgcn_mfma_f32_16x16x32_bf16(
                a[mf], bfr[nf], acc[mf][nf], 0, 0, 0);
      }
    }
  }

#pragma unroll
  for (int mf = 0; mf < 4; mf++) {
    int obase = wm * 64 + mf * 16 + kg * 4;
#pragma unroll
    for (int nf = 0; nf < 2; nf++) {
      int w = wbase + nf * 16 + ml;
      float v[4];
#pragma unroll
      for (int r4 = 0; r4 < 4; r4++) {
        int o = obase + r4;
        float val = acc[mf][nf][r4] + Bi[o];
        val = val > 0.f ? val : 0.2f * val;
        size_t idx = (((size_t)bt * 128 + o) * 64 + h) * 64 + w;
        if (RES) val += Rs[idx];
        if (WF32) Yf[idx] = val;
        v[r4] = val;
      }
      if (WBF16) {
        unsigned int lo = (unsigned int)f2bf(v[0]) | ((unsigned int)f2bf(v[1]) << 16);
        unsigned int hi = (unsigned int)f2bf(v[2]) | ((unsigned int)f2bf(v[3]) << 16);
        *(uint2*)(Ybf + (((size_t)bt * 4096 + h * 64 + w) * 128 + obase)) =
            make_uint2(lo, hi);
      }
    }
  }
}

extern "C" void kernel_launch(void* const* d_in, const int* in_sizes, int n_in,
                              void* d_out, int out_size, void* d_ws, size_t ws_size,
                              hipStream_t stream) {
  (void)in_sizes; (void)n_in; (void)out_size; (void)ws_size;
  const float* x   = (const float*)d_in[0];
  const float* Wq  = (const float*)d_in[1];
  const float* bq  = (const float*)d_in[2];
  const float* Wk  = (const float*)d_in[3];
  const float* bk  = (const float*)d_in[4];
  const float* Wv  = (const float*)d_in[5];
  const float* bv  = (const float*)d_in[6];
  const float* Wo  = (const float*)d_in[7];
  const float* bo  = (const float*)d_in[8];
  const float* Wf1 = (const float*)d_in[9];
  const float* bf1 = (const float*)d_in[10];
  const float* Wf2 = (const float*)d_in[11];
  const float* bf2 = (const float*)d_in[12];
  float* out = (float*)d_out;

  // workspace layout (~91.2 MB)
  char* wsb = (char*)d_ws;
  float* xcur = (float*)(wsb);                                  // 16 MB
  float* opk  = (float*)(wsb + 16777216);                       // 16 MB
  float* S    = (float*)(wsb + 33554432);                       //  8 MB (also Spart)
  unsigned short* Qp = (unsigned short*)(wsb + 41943040);       //  8 MB (g1-3)
  unsigned short* Kp = (unsigned short*)(wsb + 50331648);       //  8 MB (g1-3)
  unsigned short* Vt = (unsigned short*)(wsb + 58720256);       //  8 MB (g1-3)
  unsigned short* Qf = (unsigned short*)(wsb + 67108864);       //  2 MB (g0)
  unsigned short* Kf = (unsigned short*)(wsb + 69206016);       //  2 MB (g0)
  unsigned short* Vf = (unsigned short*)(wsb + 71303168);       //  2 MB (g0)
  unsigned short* att_hwc  = (unsigned short*)(wsb + 73400320); //  8 MB (=f1_hwc)
  unsigned short* xcur_hwc = (unsigned short*)(wsb + 81788928); //  8 MB (=Pb)
  unsigned short* Wt0 = (unsigned short*)(wsb + 90177536);
  unsigned short* Wt1 = (unsigned short*)(wsb + 90472448);
  unsigned short* Wt2 = (unsigned short*)(wsb + 90767360);
  unsigned short* Wqb = (unsigned short*)(wsb + 91062272);
  unsigned short* Wkb = (unsigned short*)(wsb + 91095040);
  unsigned short* Wvb = (unsigned short*)(wsb + 91127808);
  unsigned short* f1_hwc = att_hwc;
  unsigned short* Pb = xcur_hwc;

  hipMemcpyAsync(xcur, x, 16777216, hipMemcpyDeviceToDevice, stream);

  const int Ls[3] = {1024, 256, 64};
  const int Ds[3] = {512, 2048, 8192};
  dim3 blk(256);

  x2hwc<<<dim3(128, 16), blk, 0, stream>>>(x, xcur_hwc);

  for (int layer = 0; layer < 2; layer++) {
    const float* wq  = Wq  + layer * 16384;
    const float* wk  = Wk  + layer * 16384;
    const float* wv  = Wv  + layer * 16384;
    const float* bq_ = bq  + layer * 128;
    const float* bk_ = bk  + layer * 128;
    const float* bv_ = bv  + layer * 128;
    const float* wo  = Wo  + layer * 147456;
    const float* bo_ = bo  + layer * 128;
    const float* wf1 = Wf1 + layer * 147456;
    const float* bf1_ = bf1 + layer * 128;
    const float* wf2 = Wf2 + layer * 147456;
    const float* bf2_ = bf2 + layer * 128;

    wprep3<<<dim3(576, 3), blk, 0, stream>>>(wo, wf1, wf2, Wt0, Wt1, Wt2);
    wprep1<<<dim3(64, 3), blk, 0, stream>>>(wq, wk, wv, Wqb, Wkb, Wvb);

    qkv_pack<0><<<dim3(512, 2), blk, 0, stream>>>(xcur_hwc, Wqb, bq_, Qp, nullptr, Qf);
    qkv_pack<1><<<dim3(512, 2), blk, 0, stream>>>(xcur_hwc, Wkb, bk_, Kp, nullptr, Kf);
    qkv_pack<2><<<dim3(512, 2), blk, 0, stream>>>(xcur_hwc, Wvb, bv_, nullptr, Vt, Vf);

    flash_mfma<<<dim3(512), blk, 0, stream>>>(Qf, Kf, Vf, opk);

    for (int gg = 0; gg < 3; gg++) {
      int g = gg + 1;
      size_t go = (size_t)g << 20;
      int L = Ls[gg], D = Ds[gg];
      if (gg == 0) {
        // L=1024: enough M/N-parallelism, direct GEMM + looped softmax
        gemm_tn<<<dim3(L / 64, L / 64, 2), blk, 0, stream>>>(
            Qp + go, Kp + go, S, D, D, D, L, 1LL << 19, 1LL << 19, (long long)L * L);
        softmax_bf16<<<dim3(2 * L), blk, 0, stream>>>(S, Pb, L);
      } else {
        // L<=256: split-K (KC=128) partial tiles + fused sum-softmax
        int nsplit = D / 128;  // g2: 16, g3: 64
        gemm_tn_sk<<<dim3(L / 64, L / 64, 2 * nsplit), blk, 0, stream>>>(
            Qp + go, Kp + go, S, D, D, L, 1LL << 19, 1LL << 19);
        softmax_sum_bf16<<<dim3(2 * L), blk, 0, stream>>>(S, Pb, L, nsplit);
      }
      gemm_tn<<<dim3(D / 64, L / 64, 2), blk, 0, stream>>>(
          Pb, Vt + go, opk + go, L, L, L, D, (long long)L * L, 1LL << 19, 1LL << 19);
    }

    unpack_att_bf16<<<dim3(2048), blk, 0, stream>>>(opk, att_hwc);

    conv_mfma<1, true, true, true><<<dim3(512), blk, 0, stream>>>(
        att_hwc, Wt0, bo_, xcur, xcur, xcur_hwc);
    conv_mfma<2, false, true, false><<<dim3(512), blk, 0, stream>>>(
        xcur_hwc, Wt1, bf1_, nullptr, nullptr, f1_hwc);
    if (layer == 0) {
      conv_mfma<1, true, true, true><<<dim3(512), blk, 0, stream>>>(
          f1_hwc, Wt2, bf2_, xcur, xcur, xcur_hwc);
    } else {
      conv_mfma<1, true, false, true><<<dim3(512), blk, 0, stream>>>(
          f1_hwc, Wt2, bf2_, xcur, out, nullptr);
    }
  }
}